// Round 22
// baseline (458.335 us; speedup 1.0000x reference)
//
#include <hip/hip_runtime.h>
#include <hip/hip_bf16.h>

// ---- problem constants ----
#define BSZ 4
#define TT 64
#define NNODE 128
#define NFEAT 16
#define HIDD 64
#define NHEAD 4
#define RHID 256
#define LDIM 64
#define EPG 1024
#define NGRAPH (BSZ*TT)          // 256
#define NTOT (NGRAPH*NNODE)      // 32768
#define ESLOTS (EPG+NNODE)       // 1152

// ---- canonical fp32 weight buffer offsets (floats) ----
#define WOFF_G0W 0
#define WOFF_G0AS 4096
#define WOFF_G0AD 4352
#define WOFF_G0B 4608
#define WOFF_G1W 4864
#define WOFF_G1AS 70400
#define WOFF_G1AD 70656
#define WOFF_G1B 70912
#define WOFF_G2W 71168
#define WOFF_G2AS 87552
#define WOFF_G2AD 87616
#define WOFF_G2B 87680
#define WOFF_WIHF 87744
#define WOFF_WHHF 153280
#define WOFF_BIHF 415424
#define WOFF_BHHF 416448
#define WOFF_WIHB 417472
#define WOFF_WHHB 483008
#define WOFF_BIHB 745152
#define WOFF_BHHB 746176
#define WOFF_MUW 747200
#define WOFF_MUB 779968
#define WOFF_LVW 780032
#define WOFF_LVB 812800
#define WTOTAL   812864

// ---- workspace float offsets ----
#define FOFF_WBUF 4096
#define FOFF_CSR  1052672      // csr_row int[132], csr_src u16[1152]
#define FOFF_SYNC 1314816      // HX: 2*3*4*512 uints + DONE ctr @ +12288
#define FOFF_WE   1576960      // WTB (bf16 B-frag Whh, 262144 uints)
#define FOFF_BBF  1900000      // bf16 B matrices (u16 view)
#define FOFF_XFP  2756608
#define FOFF_XBP  3018752
#define FOFF_HT   3280896
#define FOFF_XSEQ 3282944
#define FOFF_PA   3291136      // P0 [32768][256] bf16
#define FOFF_PB   5388288      // P1 [32768][256] bf16
#define FOFF_P    7485440      // X  [32768][16]  bf16

// bf16 B-matrix u16 offsets inside BBF (G0/G1/G2 stored TRANSPOSED [out][in])
#define BOFF_G0 0
#define BOFF_G1 4096
#define BOFF_G2 69632
#define BOFF_WF 86016
#define BOFF_WB 151552
#define BTOTAL  217088

// setup phases
#define SP_CVTX  (WTOTAL + BTOTAL)            // 1029952
#define SP_WHH   (SP_CVTX + NTOT*NFEAT)       // 1554240
#define SP_HX    (SP_WHH + 262144)            // 1816384 (HX region start)
#define SP_TOTAL (SP_HX + 12288 + 64)         // SENT region + zeroed ctr region

#define SENT 0xFFFFFFFFu

typedef __attribute__((ext_vector_type(8))) short short8;
typedef __attribute__((ext_vector_type(4))) float float4v;

__device__ __forceinline__ float b2f(unsigned short u){
  union { unsigned int i; float f; } v; v.i = ((unsigned int)u) << 16; return v.f;
}
__device__ __forceinline__ unsigned short f2b(float f){
  __hip_bfloat16 h = __float2bfloat16(f);
  union { __hip_bfloat16 h; unsigned short u; } v; v.h = h; return v.u;
}
__device__ __forceinline__ float ldf(const void* p, int i, int flag){
  return flag ? b2f(((const unsigned short*)p)[i]) : ((const float*)p)[i];
}
__device__ __forceinline__ float h2f(unsigned short s){
  union { _Float16 hh; unsigned short s; } u; u.s = s; return (float)u.hh;
}
__device__ __forceinline__ unsigned short f2h(float f){
  union { _Float16 hh; unsigned short s; } u; u.hh = (_Float16)f; return u.s;
}
__device__ __forceinline__ int sniff32(const unsigned short* w){
  int ok = 0;
  #pragma unroll
  for (int i = 0; i < 32; ++i){
    float a = fabsf(b2f(w[2 * i]));
    if (a > 1e-8f && a < 4.f) ok++;
  }
  return ok >= 16 ? 1 : 0;
}

// ---------------- fused setup: sniff + cvtw + packb(T) + cvtx + packwhh + HX/ctr + CSR ----------------
struct CvtArgs {
  const void* src[24];
  int off[25];
};
__global__ void setup_kernel(CvtArgs a,
                             float* __restrict__ W, unsigned short* __restrict__ BBF,
                             unsigned short* __restrict__ P, unsigned int* __restrict__ WT,
                             unsigned int* __restrict__ HX,
                             const void* __restrict__ x, const int* __restrict__ ei,
                             int* __restrict__ csr_row, unsigned short* __restrict__ csr_src)
{
  __shared__ int cnt[NNODE];
  __shared__ int off[NNODE];
  __shared__ int wo[NNODE];
  const int tid = threadIdx.x;

  if (blockIdx.x == gridDim.x - 1){
    if (tid < NNODE) cnt[tid] = 0;
    __syncthreads();
    for (int i = tid; i < ESLOTS; i += 256){
      int d = (i < EPG) ? ei[EPG + i] : (i - EPG);
      atomicAdd(&cnt[d], 1);
    }
    __syncthreads();
    if (tid < NNODE) off[tid] = cnt[tid];
    for (int o = 1; o < NNODE; o <<= 1){
      __syncthreads();
      int t = (tid < NNODE && tid >= o) ? off[tid - o] : 0;
      __syncthreads();
      if (tid < NNODE) off[tid] += t;
    }
    __syncthreads();
    if (tid < NNODE){
      wo[tid] = off[tid] - cnt[tid];
      csr_row[tid + 1] = off[tid];
    }
    if (tid == 0) csr_row[0] = 0;
    __syncthreads();
    for (int i = tid; i < ESLOTS; i += 256){
      int s, d;
      if (i < EPG){ s = ei[i]; d = ei[EPG + i]; } else { s = i - EPG; d = i - EPG; }
      int pos = atomicAdd(&wo[d], 1);
      csr_src[pos] = (unsigned short)s;
    }
    return;
  }

  int id = blockIdx.x * blockDim.x + tid;
  if (id >= SP_TOTAL) return;
  int fl = sniff32((const unsigned short*)a.src[0]);
  if (id < WTOTAL){
    int k = 0;
    while (id >= a.off[k + 1]) ++k;
    W[id] = ldf(a.src[k], id - a.off[k], fl);
  } else if (id < WTOTAL + BTOTAL){
    int r = id - WTOTAL;
    float v;
    if (r < BOFF_G1){
      int o = r >> 4, k = r & 15;
      v = ldf(a.src[0], k * 256 + o, fl);
    } else if (r < BOFF_G2){
      int rr = r - BOFF_G1; int o = rr >> 8, k = rr & 255;
      v = ldf(a.src[4], k * 256 + o, fl);
    } else if (r < BOFF_WF){
      int rr = r - BOFF_G2; int o = rr >> 8, k = rr & 255;
      v = ldf(a.src[8], k * 64 + o, fl);
    } else if (r < BOFF_WB){
      int q = r - BOFF_WF; int k = q >> 10, n = q & 1023;
      v = ldf(a.src[12], n * 64 + k, fl);
    } else {
      int q = r - BOFF_WB; int k = q >> 10, n = q & 1023;
      v = ldf(a.src[16], n * 64 + k, fl);
    }
    BBF[r] = f2b(v);
  } else if (id < SP_CVTX + NTOT * NFEAT){
    int r = id - SP_CVTX;
    P[r] = fl ? ((const unsigned short*)x)[r] : f2b(((const float*)x)[r]);
  } else if (id < SP_HX){
    int r0 = id - SP_WHH;
    int c = r0 & 3;
    int lane = (r0 >> 2) & 63;
    int nt = (r0 >> 8) & 15;
    int kc = (r0 >> 12) & 7;
    int m = (r0 >> 15) & 3;
    int dir = r0 >> 17;
    int l = nt * 16 + (lane & 15);
    int u = (l >> 6) * 256 + 64 * m + (l & 63);
    int k0 = kc * 32 + ((lane >> 4) << 3) + 2 * c;
    const void* Wsrc = dir ? a.src[17] : a.src[13];
    unsigned short va = f2b(ldf(Wsrc, u * RHID + k0, fl));
    unsigned short vb = f2b(ldf(Wsrc, u * RHID + k0 + 1, fl));
    WT[r0] = (unsigned int)va | ((unsigned int)vb << 16);
  } else {
    int r0 = id - SP_HX;
    HX[r0] = (r0 < 12288) ? SENT : 0u;   // sentinel slots + zeroed done-counter region
  }
}

// ---------------- GAT 4-head half-layer kernel (L0/L1): 512 blocks, MFMA agg, plain stores ----------------
template<int KV>
__global__ __launch_bounds__(256)
void glayer_kernel(const unsigned short* __restrict__ Pin,
                   const unsigned short* __restrict__ BT,
                   const float* __restrict__ Wbuf,
                   int asoff, int adoff, int boff,
                   const int* __restrict__ csr_row, const unsigned short* __restrict__ csr_src,
                   unsigned short* __restrict__ Pout)
{
  __shared__ unsigned short HT_[128 * 136];   // h^T [col][node]
  __shared__ unsigned short AD[128 * 136];    // union: Bst / dense-alpha [dst][src]
  __shared__ unsigned short ALS16[256];
  __shared__ unsigned short ALD16[256];
  __shared__ int   rowL[132];
  __shared__ unsigned char srcL[1152];

  const int tid = threadIdx.x;
  const int g = blockIdx.x >> 1, hb = blockIdx.x & 1;
  const int c0 = hb * 128;
  const int w = tid >> 6, lane = tid & 63, q = lane >> 4, r = lane & 15;
  unsigned short* Bst = AD;

  for (int i = tid; i < 129; i += 256) rowL[i] = csr_row[i];
  for (int i = tid; i < 1152; i += 256) srcL[i] = (unsigned char)csr_src[i];
  __syncthreads();

  // ---- GEMM producing h^T ----
  {
    float4v acc0[8], acc1[8];
    #pragma unroll
    for (int i = 0; i < 8; ++i){ acc0[i] = (float4v){0,0,0,0}; acc1[i] = (float4v){0,0,0,0}; }
    const int KR = (KV + 31) / 32;
    for (int kr = 0; kr < KR; ++kr){
      const int kc = kr * 32;
      __syncthreads();
      {
        int n = tid >> 1, kb = (tid & 1) * 16;
        uint4 z = {0,0,0,0}; uint4 v0 = z, v1 = z;
        if (kb < KV)     v0 = *(const uint4*)(BT + (size_t)(c0 + n) * KV + kc + kb);
        if (kb + 8 < KV) v1 = *(const uint4*)(BT + (size_t)(c0 + n) * KV + kc + kb + 8);
        *(uint4*)&Bst[n * 40 + kb] = v0;
        *(uint4*)&Bst[n * 40 + kb + 8] = v1;
      }
      short8 a0 = {0,0,0,0,0,0,0,0}, a1 = {0,0,0,0,0,0,0,0};
      if (KV >= 32 || q < 2){
        a0 = *(const short8*)(Pin + (size_t)(g * 128 + 16 * w       + r) * KV + kc + q * 8);
        a1 = *(const short8*)(Pin + (size_t)(g * 128 + 16 * (w + 4) + r) * KV + kc + q * 8);
      }
      __syncthreads();
      #pragma unroll
      for (int nt = 0; nt < 8; ++nt){
        short8 bf = *(const short8*)&Bst[(16 * nt + r) * 40 + q * 8];
        acc0[nt] = __builtin_amdgcn_mfma_f32_16x16x32_bf16(a0, bf, acc0[nt], 0, 0, 0);
        acc1[nt] = __builtin_amdgcn_mfma_f32_16x16x32_bf16(a1, bf, acc1[nt], 0, 0, 0);
      }
    }
    __syncthreads();
    #pragma unroll
    for (int nt = 0; nt < 8; ++nt)
      #pragma unroll
      for (int i = 0; i < 4; ++i){
        HT_[(16 * nt + r) * 136 + 16 * w       + q * 4 + i] = f2b(acc0[nt][i]);
        HT_[(16 * nt + r) * 136 + 16 * (w + 4) + q * 4 + i] = f2b(acc1[nt][i]);
      }
    __syncthreads();
  }

  // ---- attention logits (2 local heads) ----
  {
    float as0 = Wbuf[asoff + c0 + 2 * lane], as1 = Wbuf[asoff + c0 + 2 * lane + 1];
    float ad0 = Wbuf[adoff + c0 + 2 * lane], ad1 = Wbuf[adoff + c0 + 2 * lane + 1];
    for (int it = 0; it < 32; ++it){
      int n = it * 4 + w;
      float e0 = b2f(HT_[(2 * lane) * 136 + n]);
      float e1 = b2f(HT_[(2 * lane + 1) * 136 + n]);
      float vs = e0 * as0 + e1 * as1;
      float vd = e0 * ad0 + e1 * ad1;
      #pragma unroll
      for (int m = 16; m >= 1; m >>= 1){ vs += __shfl_xor(vs, m); vd += __shfl_xor(vd, m); }
      if ((lane & 31) == 0){
        ALS16[n * 2 + (lane >> 5)] = f2h(vs);
        ALD16[n * 2 + (lane >> 5)] = f2h(vd);
      }
    }
  }
  __syncthreads();

  // ---- per-head: dense softmax scatter + MFMA agg + plain-store epilogue ----
  for (int hl = 0; hl < 2; ++hl){
    for (int i = tid; i < 8704; i += 256) ((unsigned int*)AD)[i] = 0;
    __syncthreads();
    if (tid < 128){
      int n = tid;
      float aldv = h2f(ALD16[n * 2 + hl]);
      int rs = rowL[n], re = rowL[n + 1];
      float mx = -3e38f, den = 0.f;
      for (int j = rs; j < re; ++j){
        float v = h2f(ALS16[srcL[j] * 2 + hl]) + aldv;
        v = v > 0.f ? v : 0.2f * v;
        if (v > mx){ den = den * __expf(mx - v) + 1.f; mx = v; }
        else den += __expf(v - mx);
      }
      float iden = 1.f / (den + 1e-16f);
      for (int j = rs; j < re; ++j){
        float v = h2f(ALS16[srcL[j] * 2 + hl]) + aldv;
        v = v > 0.f ? v : 0.2f * v;
        float al = __expf(v - mx) * iden;
        int s = srcL[j];
        AD[n * 136 + s] = f2b(b2f(AD[n * 136 + s]) + al);
      }
    }
    __syncthreads();
    float4v am[2][4];
    #pragma unroll
    for (int mt = 0; mt < 2; ++mt)
      #pragma unroll
      for (int nt = 0; nt < 4; ++nt) am[mt][nt] = (float4v){0,0,0,0};
    #pragma unroll
    for (int kc = 0; kc < 4; ++kc){
      short8 af0 = *(const short8*)&AD[(w * 32      + r) * 136 + kc * 32 + q * 8];
      short8 af1 = *(const short8*)&AD[(w * 32 + 16 + r) * 136 + kc * 32 + q * 8];
      #pragma unroll
      for (int nt = 0; nt < 4; ++nt){
        short8 bf = *(const short8*)&HT_[(hl * 64 + nt * 16 + r) * 136 + kc * 32 + q * 8];
        am[0][nt] = __builtin_amdgcn_mfma_f32_16x16x32_bf16(af0, bf, am[0][nt], 0, 0, 0);
        am[1][nt] = __builtin_amdgcn_mfma_f32_16x16x32_bf16(af1, bf, am[1][nt], 0, 0, 0);
      }
    }
    #pragma unroll
    for (int mt = 0; mt < 2; ++mt)
      #pragma unroll
      for (int nt = 0; nt < 4; ++nt){
        int col = hl * 64 + nt * 16 + r;
        float bz = Wbuf[boff + c0 + col];
        #pragma unroll
        for (int i = 0; i < 4; ++i){
          int dst = w * 32 + mt * 16 + q * 4 + i;
          float v = am[mt][nt][i] + bz;
          v = v > 0.f ? v : 0.f;
          Pout[(size_t)(g * 128 + dst) * 256 + c0 + col] = f2b(v);
        }
      }
    __syncthreads();
  }
}

// ---------------- GAT layer 2 (1 head) + pool: 512 blocks ----------------
__global__ __launch_bounds__(256)
void glayer2_kernel(const unsigned short* __restrict__ Pin,
                    const unsigned short* __restrict__ BT,
                    const float* __restrict__ Wbuf,
                    const int* __restrict__ csr_row, const unsigned short* __restrict__ csr_src,
                    unsigned short* __restrict__ XSEQ)
{
  __shared__ unsigned short HT_[64 * 136];
  __shared__ unsigned short AD[128 * 136];
  __shared__ float ALSf[128];
  __shared__ float ALDf[128];
  __shared__ int   rowL[132];
  __shared__ unsigned char srcL[1152];
  __shared__ float pools[4][64];

  const int tid = threadIdx.x;
  const int g = blockIdx.x >> 1, hb = blockIdx.x & 1;
  const int w = tid >> 6, lane = tid & 63, q = lane >> 4, r = lane & 15;
  unsigned short* Bst = AD;

  for (int i = tid; i < 129; i += 256) rowL[i] = csr_row[i];
  for (int i = tid; i < 1152; i += 256) srcL[i] = (unsigned char)csr_src[i];
  __syncthreads();

  {
    float4v acc0[4], acc1[4];
    #pragma unroll
    for (int i = 0; i < 4; ++i){ acc0[i] = (float4v){0,0,0,0}; acc1[i] = (float4v){0,0,0,0}; }
    for (int kr = 0; kr < 8; ++kr){
      const int kc = kr * 32;
      __syncthreads();
      {
        int n = tid >> 2, kb = (tid & 3) * 8;
        uint4 v = *(const uint4*)(BT + (size_t)n * 256 + kc + kb);
        *(uint4*)&Bst[n * 40 + kb] = v;
      }
      short8 a0 = *(const short8*)(Pin + (size_t)(g * 128 + 16 * w       + r) * 256 + kc + q * 8);
      short8 a1 = *(const short8*)(Pin + (size_t)(g * 128 + 16 * (w + 4) + r) * 256 + kc + q * 8);
      __syncthreads();
      #pragma unroll
      for (int nt = 0; nt < 4; ++nt){
        short8 bf = *(const short8*)&Bst[(16 * nt + r) * 40 + q * 8];
        acc0[nt] = __builtin_amdgcn_mfma_f32_16x16x32_bf16(a0, bf, acc0[nt], 0, 0, 0);
        acc1[nt] = __builtin_amdgcn_mfma_f32_16x16x32_bf16(a1, bf, acc1[nt], 0, 0, 0);
      }
    }
    __syncthreads();
    #pragma unroll
    for (int nt = 0; nt < 4; ++nt)
      #pragma unroll
      for (int i = 0; i < 4; ++i){
        HT_[(16 * nt + r) * 136 + 16 * w       + q * 4 + i] = f2b(acc0[nt][i]);
        HT_[(16 * nt + r) * 136 + 16 * (w + 4) + q * 4 + i] = f2b(acc1[nt][i]);
      }
    __syncthreads();
  }

  {
    float asv = Wbuf[WOFF_G2AS + lane];
    float adv = Wbuf[WOFF_G2AD + lane];
    for (int it = 0; it < 32; ++it){
      int n = it * 4 + w;
      float e0 = b2f(HT_[lane * 136 + n]);
      float vs = e0 * asv, vd = e0 * adv;
      #pragma unroll
      for (int m = 32; m >= 1; m >>= 1){ vs += __shfl_xor(vs, m); vd += __shfl_xor(vd, m); }
      if (lane == 0){ ALSf[n] = vs; ALDf[n] = vd; }
    }
  }
  __syncthreads();
  for (int i = tid; i < 8704; i += 256) ((unsigned int*)AD)[i] = 0;
  __syncthreads();
  if (tid < 128){
    int n = tid;
    float aldv = ALDf[n];
    int rs = rowL[n], re = rowL[n + 1];
    float mx = -3e38f, den = 0.f;
    for (int j = rs; j < re; ++j){
      float v = ALSf[srcL[j]] + aldv;
      v = v > 0.f ? v : 0.2f * v;
      if (v > mx){ den = den * __expf(mx - v) + 1.f; mx = v; }
      else den += __expf(v - mx);
    }
    float iden = 1.f / (den + 1e-16f);
    for (int j = rs; j < re; ++j){
      float v = ALSf[srcL[j]] + aldv;
      v = v > 0.f ? v : 0.2f * v;
      float al = __expf(v - mx) * iden;
      int s = srcL[j];
      AD[n * 136 + s] = f2b(b2f(AD[n * 136 + s]) + al);
    }
  }
  __syncthreads();
  float4v am[2][4];
  #pragma unroll
  for (int mt = 0; mt < 2; ++mt)
    #pragma unroll
    for (int nt = 0; nt < 4; ++nt) am[mt][nt] = (float4v){0,0,0,0};
  #pragma unroll
  for (int kc = 0; kc < 4; ++kc){
    short8 af0 = *(const short8*)&AD[(w * 32      + r) * 136 + kc * 32 + q * 8];
    short8 af1 = *(const short8*)&AD[(w * 32 + 16 + r) * 136 + kc * 32 + q * 8];
    #pragma unroll
    for (int nt = 0; nt < 4; ++nt){
      short8 bf = *(const short8*)&HT_[(nt * 16 + r) * 136 + kc * 32 + q * 8];
      am[0][nt] = __builtin_amdgcn_mfma_f32_16x16x32_bf16(af0, bf, am[0][nt], 0, 0, 0);
      am[1][nt] = __builtin_amdgcn_mfma_f32_16x16x32_bf16(af1, bf, am[1][nt], 0, 0, 0);
    }
  }
  float psum[4] = {0.f, 0.f, 0.f, 0.f};
  #pragma unroll
  for (int nt = 0; nt < 4; ++nt){
    int col = nt * 16 + r;
    float bz = Wbuf[WOFF_G2B + col];
    #pragma unroll
    for (int mt = 0; mt < 2; ++mt)
      #pragma unroll
      for (int i = 0; i < 4; ++i){
        float v = am[mt][nt][i] + bz;
        psum[nt] += (v > 0.f ? v : 0.f);
      }
    psum[nt] += __shfl_xor(psum[nt], 16);
    psum[nt] += __shfl_xor(psum[nt], 32);
  }
  if (q == 0){
    #pragma unroll
    for (int nt = 0; nt < 4; ++nt) pools[w][nt * 16 + r] = psum[nt];
  }
  __syncthreads();
  if (tid < 64 && (tid >> 5) == hb){
    float s = pools[0][tid] + pools[1][tid] + pools[2][tid] + pools[3][tid];
    int b = g >> 6, tq = g & 63;
    XSEQ[(size_t)(tq * BSZ + b) * HIDD + tid] = f2b(s);
  }
}

// ---------------- MFMA matmul for BOTH Wih GEMMs in one launch (z = dir) ----------------
__global__ __launch_bounds__(256)
void mmx2_kernel(const unsigned short* __restrict__ A,
                 const unsigned short* __restrict__ B0, const unsigned short* __restrict__ B1,
                 float* __restrict__ C0, float* __restrict__ C1, int M, int Nc, int K)
{
  __shared__ unsigned short As[64][40];
  __shared__ unsigned short Bs[64][40];
  const unsigned short* Bb = blockIdx.z ? B1 : B0;
  float* C = blockIdx.z ? C1 : C0;
  const int tid = threadIdx.x;
  const int w = tid >> 6, lane = tid & 63, q = lane >> 4, r = lane & 15;
  const int m0 = blockIdx.x * 64, n0 = blockIdx.y * 64;
  float4v acc0 = {0,0,0,0}, acc1 = {0,0,0,0}, acc2 = {0,0,0,0}, acc3 = {0,0,0,0};
  const int arow = tid >> 2, akb = (tid & 3) * 8;
  const int bk = tid >> 3, bnb = (tid & 7) * 8;
  for (int kc = 0; kc < K; kc += 32){
    int kw = K - kc; if (kw > 32) kw = 32;
    if (akb < kw){
      uint4 v = *(const uint4*)(A + (size_t)(m0 + arow) * K + kc + akb);
      *(uint4*)&As[arow][akb] = v;
    } else {
      uint4 z = {0,0,0,0}; *(uint4*)&As[arow][akb] = z;
    }
    if (bk < kw){
      uint4 v = *(const uint4*)(Bb + (size_t)(kc + bk) * Nc + n0 + bnb);
      const unsigned short* vs = (const unsigned short*)&v;
      #pragma unroll
      for (int e = 0; e < 8; ++e) Bs[bnb + e][bk] = vs[e];
    } else {
      #pragma unroll
      for (int e = 0; e < 8; ++e) Bs[bnb + e][bk] = 0;
    }
    __syncthreads();
    short8 af = *(const short8*)&As[16 * w + r][q * 8];
    short8 b0 = *(const short8*)&Bs[r][q * 8];
    short8 b1 = *(const short8*)&Bs[16 + r][q * 8];
    short8 b2 = *(const short8*)&Bs[32 + r][q * 8];
    short8 b3 = *(const short8*)&Bs[48 + r][q * 8];
    acc0 = __builtin_amdgcn_mfma_f32_16x16x32_bf16(af, b0, acc0, 0, 0, 0);
    acc1 = __builtin_amdgcn_mfma_f32_16x16x32_bf16(af, b1, acc1, 0, 0, 0);
    acc2 = __builtin_amdgcn_mfma_f32_16x16x32_bf16(af, b2, acc2, 0, 0, 0);
    acc3 = __builtin_amdgcn_mfma_f32_16x16x32_bf16(af, b3, acc3, 0, 0, 0);
    __syncthreads();
  }
  const int row = m0 + 16 * w + q * 4, col0 = n0 + r;
  #pragma unroll
  for (int i = 0; i < 4; ++i){
    size_t base = (size_t)(row + i) * Nc;
    C[base + col0]      = acc0[i];
    C[base + col0 + 16] = acc1[i];
    C[base + col0 + 32] = acc2[i];
    C[base + col0 + 48] = acc3[i];
  }
}

// ---------------- LSTM via MFMA + fused head: 8 WGs, sentinel sync, 2-barrier step ----------------
__global__ __launch_bounds__(256)
void lstm14_kernel(const float* __restrict__ XF, const float* __restrict__ XB,
                   const unsigned int* __restrict__ WT,
                   const float* __restrict__ Wbuf,
                   unsigned int* __restrict__ HX,
                   float* __restrict__ HT,
                   float* __restrict__ out)
{
  __shared__ unsigned int WL[32768];
  __shared__ unsigned int H16[16 * 132];
  __shared__ float glds[4][256];
  __shared__ float muv[4][64];
  __shared__ float lvv[4][64];

  const int tid = threadIdx.x;
  const int m = blockIdx.x & 3, dir = blockIdx.x >> 2;
  const int w = tid >> 6, lane = tid & 63, quad = lane >> 4, r = lane & 15;
  const float* Xp = dir ? XB : XF;
  const int ub = tid >> 6, uj = tid & 63;
  unsigned int* HXd = HX + dir * 6144;
  int* DONE = (int*)(HX + 12288);

  const float* bi = Wbuf + (dir ? WOFF_BIHB : WOFF_BIHF);
  const float* bh = Wbuf + (dir ? WOFF_BHHB : WOFF_BHHF);
  float bias0 = bi[0 * 256 + 64 * m + uj] + bh[0 * 256 + 64 * m + uj];
  float bias1 = bi[1 * 256 + 64 * m + uj] + bh[1 * 256 + 64 * m + uj];
  float bias2 = bi[2 * 256 + 64 * m + uj] + bh[2 * 256 + 64 * m + uj];
  float bias3 = bi[3 * 256 + 64 * m + uj] + bh[3 * 256 + 64 * m + uj];

  {
    const uint4* WT4 = (const uint4*)(WT + dir * 131072 + m * 32768);
    uint4* WL4 = (uint4*)WL;
    #pragma unroll
    for (int s = 0; s < 32; ++s)
      WL4[s * 256 + tid] = WT4[s * 256 + tid];
  }
  for (int i = tid; i < 16 * 132; i += 256) H16[i] = 0;
  float c = 0.f;
  __syncthreads();

  const uint4* WL4 = (const uint4*)WL;
  const uint4* H16u4 = (const uint4*)H16;

  float4v acc[4];
  auto kchunk = [&](int kc){
    uint4 av = H16u4[(lane & 15) * 33 + kc * 4 + quad];
    short8 af = *(const short8*)&av;
    #pragma unroll
    for (int t = 0; t < 4; ++t){
      int nt = w * 4 + t;
      uint4 bv = WL4[(kc * 16 + nt) * 64 + lane];
      short8 bf = *(const short8*)&bv;
      acc[t] = __builtin_amdgcn_mfma_f32_16x16x32_bf16(af, bf, acc[t], 0, 0, 0);
    }
  };

  for (int t = 0; t < TT; ++t){
    const int tb = dir ? (TT - 1 - t) : t;
    const float* xr = Xp + (size_t)(tb * 4 + ub) * 1024 + 64 * m + uj;
    float x0 = xr[0], x1 = xr[256], x2 = xr[512], x3 = xr[768];

    #pragma unroll
    for (int i = 0; i < 4; ++i) acc[i] = (float4v){0,0,0,0};

    // Phase B FIRST (2-barrier step): fetch peer slices of h(t-1), poll payload
    if (t > 0 && w > 0){
      int qp = (m + w) & 3;
      unsigned int* S = HXd + ((t - 1) % 3) * 2048 + m * 512;
      int b2 = lane >> 5, p2 = lane & 31;
      int i1G = b2 * 128 + 32 * qp + p2;
      int i2G = (b2 + 2) * 128 + 32 * qp + p2;
      int i1L = b2 * 132 + 32 * qp + p2;
      int i2L = (b2 + 2) * 132 + 32 * qp + p2;
      unsigned int v1, v2;
      int guard = 0;
      while ((v1 = __hip_atomic_load(&S[i1G], __ATOMIC_RELAXED, __HIP_MEMORY_SCOPE_AGENT)) == SENT
             && guard < 200000){ __builtin_amdgcn_s_sleep(1); ++guard; }
      guard = 0;
      while ((v2 = __hip_atomic_load(&S[i2G], __ATOMIC_RELAXED, __HIP_MEMORY_SCOPE_AGENT)) == SENT
             && guard < 200000){ __builtin_amdgcn_s_sleep(1); ++guard; }
      H16[i1L] = v1; H16[i2L] = v2;
      __hip_atomic_store(&S[i1G], SENT, __ATOMIC_RELAXED, __HIP_MEMORY_SCOPE_AGENT);
      __hip_atomic_store(&S[i2G], SENT, __ATOMIC_RELAXED, __HIP_MEMORY_SCOPE_AGENT);
    }
    __syncthreads();      // orders publishes(t-1) + fetches(t) before reads

    // all 8 k-chunks
    #pragma unroll
    for (int i = 0; i < 4; ++i){
      int qp = (m + i) & 3;
      kchunk(2 * qp); kchunk(2 * qp + 1);
    }
    if (quad == 0){
      #pragma unroll
      for (int tt = 0; tt < 4; ++tt){
        int l = (w * 4 + tt) * 16 + r;
        glds[0][l] = acc[tt][0];
        glds[1][l] = acc[tt][1];
        glds[2][l] = acc[tt][2];
        glds[3][l] = acc[tt][3];
      }
    }
    __syncthreads();

    float gi = glds[ub][uj]        + bias0 + x0;
    float gf = glds[ub][64 + uj]   + bias1 + x1;
    float gg = glds[ub][128 + uj]  + bias2 + x2;
    float go = glds[ub][192 + uj]  + bias3 + x3;
    float si = 1.f / (1.f + __expf(-gi));
    float sf = 1.f / (1.f + __expf(-gf));
    float so = 1.f / (1.f + __expf(-go));
    float tg = 1.f - 2.f / (1.f + __expf(2.f * gg));
    c = sf * c + si * tg;
    float ch = 1.f - 2.f / (1.f + __expf(2.f * c));
    float hval = so * ch;
    if (t == TT - 1){
      HT[(size_t)(dir * 4 + ub) * RHID + (64 * m + uj)] = hval;
      break;
    }
    unsigned int own = f2b(hval);
    unsigned int partner = ((unsigned int)__shfl_xor((int)own, 1)) & 0xffffu;
    unsigned int* S = HXd + (t % 3) * 2048;
    if ((uj & 1) == 0){
      unsigned int v = own | (partner << 16);
      int p = uj >> 1;
      int idxG = ub * 128 + 32 * m + p;
      int idxL = ub * 132 + 32 * m + p;
      H16[idxL] = v;
      #pragma unroll
      for (int cns = 1; cns < 4; ++cns)
        __hip_atomic_store(&S[((m + cns) & 3) * 512 + idxG], v,
                           __ATOMIC_RELAXED, __HIP_MEMORY_SCOPE_AGENT);
    }
    // no trailing barrier: next step's post-poll barrier provides the ordering
  }

  // ---- fused head: all 8 WGs signal; block 0 computes mu/logvar + Poincare ----
  __syncthreads();                       // drains HT stores (vmcnt) before release
  if (tid == 0)
    __hip_atomic_fetch_add(DONE, 1, __ATOMIC_RELEASE, __HIP_MEMORY_SCOPE_AGENT);
  if (blockIdx.x != 0) return;
  if (tid == 0){
    int guard = 0;
    while (__hip_atomic_load(DONE, __ATOMIC_ACQUIRE, __HIP_MEMORY_SCOPE_AGENT) < 8
           && guard < 2000000){ __builtin_amdgcn_s_sleep(1); ++guard; }
  }
  __syncthreads();
  for (int job = w; job < 512; job += 4){
    int j = job & 63, b = (job >> 6) & 3, mat = job >> 8;
    const float* W = Wbuf + (mat ? WOFF_LVW : WOFF_MUW) + (size_t)j * 512;
    float s = 0.f;
    #pragma unroll
    for (int e = 0; e < 8; ++e){
      int dk = lane * 8 + e;
      float fv = HT[((dk >> 8) * 4 + b) * 256 + (dk & 255)];
      s += W[dk] * fv;
    }
    #pragma unroll
    for (int mm = 32; mm >= 1; mm >>= 1) s += __shfl_xor(s, mm);
    if (lane == 0){
      float v = s + Wbuf[(mat ? WOFF_LVB : WOFF_MUB) + j];
      if (mat) lvv[b][j] = v; else muv[b][j] = v;
    }
  }
  __syncthreads();
  {
    int b = tid >> 6, j = tid & 63;
    float mu = muv[b][j];
    float sq = mu * mu;
    #pragma unroll
    for (int mm = 32; mm >= 1; mm >>= 1) sq += __shfl_xor(sq, mm);
    float nrm = sqrtf(sq);
    const float mxn = 1.0f - 4e-3f;
    if (nrm > mxn) mu = mu / nrm * mxn;
    out[b * 64 + j] = mu;
    out[256 + b * 64 + j] = lvv[b][j];
  }
}

extern "C" void kernel_launch(void* const* d_in, const int* in_sizes, int n_in,
                              void* d_out, int out_size, void* d_ws, size_t ws_size,
                              hipStream_t stream)
{
  const int* ei = (const int*)d_in[1];

  float* FW   = (float*)d_ws;
  float* Wbuf = FW + FOFF_WBUF;
  int*   csr_row = (int*)(FW + FOFF_CSR);
  unsigned short* csr_src = (unsigned short*)(FW + FOFF_CSR + 132);
  float* XFp  = FW + FOFF_XFP;
  float* XBp  = FW + FOFF_XBP;
  float* HT   = FW + FOFF_HT;
  unsigned short* XSEQ = (unsigned short*)(FW + FOFF_XSEQ);
  unsigned short* PA   = (unsigned short*)(FW + FOFF_PA);
  unsigned short* PB   = (unsigned short*)(FW + FOFF_PB);
  unsigned short* Pb   = (unsigned short*)(FW + FOFF_P);
  unsigned int*   WT   = (unsigned int*)(FW + FOFF_WE);
  unsigned short* BBF  = (unsigned short*)(FW + FOFF_BBF);
  unsigned int*   HX   = (unsigned int*)(FW + FOFF_SYNC);

  CvtArgs ca;
  static const int wsz[24] = {4096,256,256,256, 65536,256,256,256, 16384,64,64,64,
                              65536,262144,1024,1024, 65536,262144,1024,1024,
                              32768,64,32768,64};
  {
    int acc = 0;
    for (int k = 0; k < 24; ++k){ ca.src[k] = d_in[2 + k]; ca.off[k] = acc; acc += wsz[k]; }
    ca.off[24] = acc;
  }
  int nblk = (SP_TOTAL + 255) / 256 + 1;
  setup_kernel<<<nblk, 256, 0, stream>>>(ca, Wbuf, BBF, Pb, WT, HX,
                                         d_in[0], ei, csr_row, csr_src);

  glayer_kernel<16><<<512, 256, 0, stream>>>(Pb, BBF + BOFF_G0, Wbuf,
                                             WOFF_G0AS, WOFF_G0AD, WOFF_G0B,
                                             csr_row, csr_src, PA);
  glayer_kernel<256><<<512, 256, 0, stream>>>(PA, BBF + BOFF_G1, Wbuf,
                                              WOFF_G1AS, WOFF_G1AD, WOFF_G1B,
                                              csr_row, csr_src, PB);
  glayer2_kernel<<<512, 256, 0, stream>>>(PB, BBF + BOFF_G2, Wbuf,
                                          csr_row, csr_src, XSEQ);

  mmx2_kernel<<<dim3(4, 16, 2), 256, 0, stream>>>(XSEQ, BBF + BOFF_WF, BBF + BOFF_WB,
                                                  XFp, XBp, 256, 1024, 64);

  // LSTM + fused head (writes d_out directly)
  lstm14_kernel<<<8, 256, 0, stream>>>(XFp, XBp, WT, Wbuf, HX, HT, (float*)d_out);
}

// Round 23
// 449.722 us; speedup vs baseline: 1.0192x; 1.0192x over previous
//
#include <hip/hip_runtime.h>
#include <hip/hip_bf16.h>

// ---- problem constants ----
#define BSZ 4
#define TT 64
#define NNODE 128
#define NFEAT 16
#define HIDD 64
#define NHEAD 4
#define RHID 256
#define LDIM 64
#define EPG 1024
#define NGRAPH (BSZ*TT)          // 256
#define NTOT (NGRAPH*NNODE)      // 32768
#define ESLOTS (EPG+NNODE)       // 1152

// ---- canonical fp32 weight buffer offsets (floats) ----
#define WOFF_G0W 0
#define WOFF_G0AS 4096
#define WOFF_G0AD 4352
#define WOFF_G0B 4608
#define WOFF_G1W 4864
#define WOFF_G1AS 70400
#define WOFF_G1AD 70656
#define WOFF_G1B 70912
#define WOFF_G2W 71168
#define WOFF_G2AS 87552
#define WOFF_G2AD 87616
#define WOFF_G2B 87680
#define WOFF_WIHF 87744
#define WOFF_WHHF 153280
#define WOFF_BIHF 415424
#define WOFF_BHHF 416448
#define WOFF_WIHB 417472
#define WOFF_WHHB 483008
#define WOFF_BIHB 745152
#define WOFF_BHHB 746176
#define WOFF_MUW 747200
#define WOFF_MUB 779968
#define WOFF_LVW 780032
#define WOFF_LVB 812800
#define WTOTAL   812864

// ---- workspace float offsets ----
#define FOFF_WBUF 4096
#define FOFF_CSR  1052672      // csr_row int[132], csr_src u16[1152]
#define FOFF_SYNC 1314816      // HX: 2*3*4*512 uints + DONE ctr @ +12288
#define FOFF_WE   1576960      // WTB (bf16 B-frag Whh, 262144 uints)
#define FOFF_BBF  1900000      // bf16 B matrices (u16 view)
#define FOFF_XFP  2756608
#define FOFF_XBP  3018752
#define FOFF_HT   3280896
#define FOFF_XSEQ 3282944
#define FOFF_PA   3291136      // P0 [32768][256] bf16
#define FOFF_PB   5388288      // P1 [32768][256] bf16
#define FOFF_P    7485440      // X  [32768][16]  bf16

// bf16 B-matrix u16 offsets inside BBF (G0/G1/G2 stored TRANSPOSED [out][in])
#define BOFF_G0 0
#define BOFF_G1 4096
#define BOFF_G2 69632
#define BOFF_WF 86016
#define BOFF_WB 151552
#define BTOTAL  217088

// setup phases
#define SP_CVTX  (WTOTAL + BTOTAL)            // 1029952
#define SP_WHH   (SP_CVTX + NTOT*NFEAT)       // 1554240
#define SP_HX    (SP_WHH + 262144)            // 1816384 (HX region start)
#define SP_TOTAL (SP_HX + 12288 + 64)         // SENT region + zeroed ctr region

#define SENT 0xFFFFFFFFu

typedef __attribute__((ext_vector_type(8))) short short8;
typedef __attribute__((ext_vector_type(4))) float float4v;

__device__ __forceinline__ float b2f(unsigned short u){
  union { unsigned int i; float f; } v; v.i = ((unsigned int)u) << 16; return v.f;
}
__device__ __forceinline__ unsigned short f2b(float f){
  __hip_bfloat16 h = __float2bfloat16(f);
  union { __hip_bfloat16 h; unsigned short u; } v; v.h = h; return v.u;
}
__device__ __forceinline__ float ldf(const void* p, int i, int flag){
  return flag ? b2f(((const unsigned short*)p)[i]) : ((const float*)p)[i];
}
__device__ __forceinline__ float h2f(unsigned short s){
  union { _Float16 hh; unsigned short s; } u; u.s = s; return (float)u.hh;
}
__device__ __forceinline__ unsigned short f2h(float f){
  union { _Float16 hh; unsigned short s; } u; u.hh = (_Float16)f; return u.s;
}
__device__ __forceinline__ int sniff32(const unsigned short* w){
  int ok = 0;
  #pragma unroll
  for (int i = 0; i < 32; ++i){
    float a = fabsf(b2f(w[2 * i]));
    if (a > 1e-8f && a < 4.f) ok++;
  }
  return ok >= 16 ? 1 : 0;
}

// ---------------- fused setup: sniff + cvtw + packb(T) + cvtx + packwhh + HX/ctr + CSR ----------------
struct CvtArgs {
  const void* src[24];
  int off[25];
};
__global__ void setup_kernel(CvtArgs a,
                             float* __restrict__ W, unsigned short* __restrict__ BBF,
                             unsigned short* __restrict__ P, unsigned int* __restrict__ WT,
                             unsigned int* __restrict__ HX,
                             const void* __restrict__ x, const int* __restrict__ ei,
                             int* __restrict__ csr_row, unsigned short* __restrict__ csr_src)
{
  __shared__ int cnt[NNODE];
  __shared__ int off[NNODE];
  __shared__ int wo[NNODE];
  const int tid = threadIdx.x;

  if (blockIdx.x == gridDim.x - 1){
    if (tid < NNODE) cnt[tid] = 0;
    __syncthreads();
    for (int i = tid; i < ESLOTS; i += 256){
      int d = (i < EPG) ? ei[EPG + i] : (i - EPG);
      atomicAdd(&cnt[d], 1);
    }
    __syncthreads();
    if (tid < NNODE) off[tid] = cnt[tid];
    for (int o = 1; o < NNODE; o <<= 1){
      __syncthreads();
      int t = (tid < NNODE && tid >= o) ? off[tid - o] : 0;
      __syncthreads();
      if (tid < NNODE) off[tid] += t;
    }
    __syncthreads();
    if (tid < NNODE){
      wo[tid] = off[tid] - cnt[tid];
      csr_row[tid + 1] = off[tid];
    }
    if (tid == 0) csr_row[0] = 0;
    __syncthreads();
    for (int i = tid; i < ESLOTS; i += 256){
      int s, d;
      if (i < EPG){ s = ei[i]; d = ei[EPG + i]; } else { s = i - EPG; d = i - EPG; }
      int pos = atomicAdd(&wo[d], 1);
      csr_src[pos] = (unsigned short)s;
    }
    return;
  }

  int id = blockIdx.x * blockDim.x + tid;
  if (id >= SP_TOTAL) return;
  int fl = sniff32((const unsigned short*)a.src[0]);
  if (id < WTOTAL){
    int k = 0;
    while (id >= a.off[k + 1]) ++k;
    W[id] = ldf(a.src[k], id - a.off[k], fl);
  } else if (id < WTOTAL + BTOTAL){
    int r = id - WTOTAL;
    float v;
    if (r < BOFF_G1){
      int o = r >> 4, k = r & 15;
      v = ldf(a.src[0], k * 256 + o, fl);
    } else if (r < BOFF_G2){
      int rr = r - BOFF_G1; int o = rr >> 8, k = rr & 255;
      v = ldf(a.src[4], k * 256 + o, fl);
    } else if (r < BOFF_WF){
      int rr = r - BOFF_G2; int o = rr >> 8, k = rr & 255;
      v = ldf(a.src[8], k * 64 + o, fl);
    } else if (r < BOFF_WB){
      int q = r - BOFF_WF; int k = q >> 10, n = q & 1023;
      v = ldf(a.src[12], n * 64 + k, fl);
    } else {
      int q = r - BOFF_WB; int k = q >> 10, n = q & 1023;
      v = ldf(a.src[16], n * 64 + k, fl);
    }
    BBF[r] = f2b(v);
  } else if (id < SP_CVTX + NTOT * NFEAT){
    int r = id - SP_CVTX;
    P[r] = fl ? ((const unsigned short*)x)[r] : f2b(((const float*)x)[r]);
  } else if (id < SP_HX){
    int r0 = id - SP_WHH;
    int c = r0 & 3;
    int lane = (r0 >> 2) & 63;
    int nt = (r0 >> 8) & 15;
    int kc = (r0 >> 12) & 7;
    int m = (r0 >> 15) & 3;
    int dir = r0 >> 17;
    int l = nt * 16 + (lane & 15);
    int u = (l >> 6) * 256 + 64 * m + (l & 63);
    int k0 = kc * 32 + ((lane >> 4) << 3) + 2 * c;
    const void* Wsrc = dir ? a.src[17] : a.src[13];
    unsigned short va = f2b(ldf(Wsrc, u * RHID + k0, fl));
    unsigned short vb = f2b(ldf(Wsrc, u * RHID + k0 + 1, fl));
    WT[r0] = (unsigned int)va | ((unsigned int)vb << 16);
  } else {
    int r0 = id - SP_HX;
    HX[r0] = (r0 < 12288) ? SENT : 0u;   // sentinel slots + zeroed done-counter region
  }
}

// ---------------- GAT 4-head half-layer kernel (L0/L1): 512 blocks, MFMA agg, plain stores ----------------
template<int KV>
__global__ __launch_bounds__(256)
void glayer_kernel(const unsigned short* __restrict__ Pin,
                   const unsigned short* __restrict__ BT,
                   const float* __restrict__ Wbuf,
                   int asoff, int adoff, int boff,
                   const int* __restrict__ csr_row, const unsigned short* __restrict__ csr_src,
                   unsigned short* __restrict__ Pout)
{
  __shared__ unsigned short HT_[128 * 136];   // h^T [col][node]
  __shared__ unsigned short AD[128 * 136];    // union: Bst / dense-alpha [dst][src]
  __shared__ unsigned short ALS16[256];
  __shared__ unsigned short ALD16[256];
  __shared__ int   rowL[132];
  __shared__ unsigned char srcL[1152];

  const int tid = threadIdx.x;
  const int g = blockIdx.x >> 1, hb = blockIdx.x & 1;
  const int c0 = hb * 128;
  const int w = tid >> 6, lane = tid & 63, q = lane >> 4, r = lane & 15;
  unsigned short* Bst = AD;

  for (int i = tid; i < 129; i += 256) rowL[i] = csr_row[i];
  for (int i = tid; i < 1152; i += 256) srcL[i] = (unsigned char)csr_src[i];
  __syncthreads();

  // ---- GEMM producing h^T ----
  {
    float4v acc0[8], acc1[8];
    #pragma unroll
    for (int i = 0; i < 8; ++i){ acc0[i] = (float4v){0,0,0,0}; acc1[i] = (float4v){0,0,0,0}; }
    const int KR = (KV + 31) / 32;
    for (int kr = 0; kr < KR; ++kr){
      const int kc = kr * 32;
      __syncthreads();
      {
        int n = tid >> 1, kb = (tid & 1) * 16;
        uint4 z = {0,0,0,0}; uint4 v0 = z, v1 = z;
        if (kb < KV)     v0 = *(const uint4*)(BT + (size_t)(c0 + n) * KV + kc + kb);
        if (kb + 8 < KV) v1 = *(const uint4*)(BT + (size_t)(c0 + n) * KV + kc + kb + 8);
        *(uint4*)&Bst[n * 40 + kb] = v0;
        *(uint4*)&Bst[n * 40 + kb + 8] = v1;
      }
      short8 a0 = {0,0,0,0,0,0,0,0}, a1 = {0,0,0,0,0,0,0,0};
      if (KV >= 32 || q < 2){
        a0 = *(const short8*)(Pin + (size_t)(g * 128 + 16 * w       + r) * KV + kc + q * 8);
        a1 = *(const short8*)(Pin + (size_t)(g * 128 + 16 * (w + 4) + r) * KV + kc + q * 8);
      }
      __syncthreads();
      #pragma unroll
      for (int nt = 0; nt < 8; ++nt){
        short8 bf = *(const short8*)&Bst[(16 * nt + r) * 40 + q * 8];
        acc0[nt] = __builtin_amdgcn_mfma_f32_16x16x32_bf16(a0, bf, acc0[nt], 0, 0, 0);
        acc1[nt] = __builtin_amdgcn_mfma_f32_16x16x32_bf16(a1, bf, acc1[nt], 0, 0, 0);
      }
    }
    __syncthreads();
    #pragma unroll
    for (int nt = 0; nt < 8; ++nt)
      #pragma unroll
      for (int i = 0; i < 4; ++i){
        HT_[(16 * nt + r) * 136 + 16 * w       + q * 4 + i] = f2b(acc0[nt][i]);
        HT_[(16 * nt + r) * 136 + 16 * (w + 4) + q * 4 + i] = f2b(acc1[nt][i]);
      }
    __syncthreads();
  }

  // ---- attention logits (2 local heads) ----
  {
    float as0 = Wbuf[asoff + c0 + 2 * lane], as1 = Wbuf[asoff + c0 + 2 * lane + 1];
    float ad0 = Wbuf[adoff + c0 + 2 * lane], ad1 = Wbuf[adoff + c0 + 2 * lane + 1];
    for (int it = 0; it < 32; ++it){
      int n = it * 4 + w;
      float e0 = b2f(HT_[(2 * lane) * 136 + n]);
      float e1 = b2f(HT_[(2 * lane + 1) * 136 + n]);
      float vs = e0 * as0 + e1 * as1;
      float vd = e0 * ad0 + e1 * ad1;
      #pragma unroll
      for (int m = 16; m >= 1; m >>= 1){ vs += __shfl_xor(vs, m); vd += __shfl_xor(vd, m); }
      if ((lane & 31) == 0){
        ALS16[n * 2 + (lane >> 5)] = f2h(vs);
        ALD16[n * 2 + (lane >> 5)] = f2h(vd);
      }
    }
  }
  __syncthreads();

  // ---- per-head: dense softmax scatter + MFMA agg + plain-store epilogue ----
  for (int hl = 0; hl < 2; ++hl){
    for (int i = tid; i < 8704; i += 256) ((unsigned int*)AD)[i] = 0;
    __syncthreads();
    if (tid < 128){
      int n = tid;
      float aldv = h2f(ALD16[n * 2 + hl]);
      int rs = rowL[n], re = rowL[n + 1];
      float mx = -3e38f, den = 0.f;
      for (int j = rs; j < re; ++j){
        float v = h2f(ALS16[srcL[j] * 2 + hl]) + aldv;
        v = v > 0.f ? v : 0.2f * v;
        if (v > mx){ den = den * __expf(mx - v) + 1.f; mx = v; }
        else den += __expf(v - mx);
      }
      float iden = 1.f / (den + 1e-16f);
      for (int j = rs; j < re; ++j){
        float v = h2f(ALS16[srcL[j] * 2 + hl]) + aldv;
        v = v > 0.f ? v : 0.2f * v;
        float al = __expf(v - mx) * iden;
        int s = srcL[j];
        AD[n * 136 + s] = f2b(b2f(AD[n * 136 + s]) + al);
      }
    }
    __syncthreads();
    float4v am[2][4];
    #pragma unroll
    for (int mt = 0; mt < 2; ++mt)
      #pragma unroll
      for (int nt = 0; nt < 4; ++nt) am[mt][nt] = (float4v){0,0,0,0};
    #pragma unroll
    for (int kc = 0; kc < 4; ++kc){
      short8 af0 = *(const short8*)&AD[(w * 32      + r) * 136 + kc * 32 + q * 8];
      short8 af1 = *(const short8*)&AD[(w * 32 + 16 + r) * 136 + kc * 32 + q * 8];
      #pragma unroll
      for (int nt = 0; nt < 4; ++nt){
        short8 bf = *(const short8*)&HT_[(hl * 64 + nt * 16 + r) * 136 + kc * 32 + q * 8];
        am[0][nt] = __builtin_amdgcn_mfma_f32_16x16x32_bf16(af0, bf, am[0][nt], 0, 0, 0);
        am[1][nt] = __builtin_amdgcn_mfma_f32_16x16x32_bf16(af1, bf, am[1][nt], 0, 0, 0);
      }
    }
    #pragma unroll
    for (int mt = 0; mt < 2; ++mt)
      #pragma unroll
      for (int nt = 0; nt < 4; ++nt){
        int col = hl * 64 + nt * 16 + r;
        float bz = Wbuf[boff + c0 + col];
        #pragma unroll
        for (int i = 0; i < 4; ++i){
          int dst = w * 32 + mt * 16 + q * 4 + i;
          float v = am[mt][nt][i] + bz;
          v = v > 0.f ? v : 0.f;
          Pout[(size_t)(g * 128 + dst) * 256 + c0 + col] = f2b(v);
        }
      }
    __syncthreads();
  }
}

// ---------------- GAT layer 2 (1 head) + pool: 512 blocks ----------------
__global__ __launch_bounds__(256)
void glayer2_kernel(const unsigned short* __restrict__ Pin,
                    const unsigned short* __restrict__ BT,
                    const float* __restrict__ Wbuf,
                    const int* __restrict__ csr_row, const unsigned short* __restrict__ csr_src,
                    unsigned short* __restrict__ XSEQ)
{
  __shared__ unsigned short HT_[64 * 136];
  __shared__ unsigned short AD[128 * 136];
  __shared__ float ALSf[128];
  __shared__ float ALDf[128];
  __shared__ int   rowL[132];
  __shared__ unsigned char srcL[1152];
  __shared__ float pools[4][64];

  const int tid = threadIdx.x;
  const int g = blockIdx.x >> 1, hb = blockIdx.x & 1;
  const int w = tid >> 6, lane = tid & 63, q = lane >> 4, r = lane & 15;
  unsigned short* Bst = AD;

  for (int i = tid; i < 129; i += 256) rowL[i] = csr_row[i];
  for (int i = tid; i < 1152; i += 256) srcL[i] = (unsigned char)csr_src[i];
  __syncthreads();

  {
    float4v acc0[4], acc1[4];
    #pragma unroll
    for (int i = 0; i < 4; ++i){ acc0[i] = (float4v){0,0,0,0}; acc1[i] = (float4v){0,0,0,0}; }
    for (int kr = 0; kr < 8; ++kr){
      const int kc = kr * 32;
      __syncthreads();
      {
        int n = tid >> 2, kb = (tid & 3) * 8;
        uint4 v = *(const uint4*)(BT + (size_t)n * 256 + kc + kb);
        *(uint4*)&Bst[n * 40 + kb] = v;
      }
      short8 a0 = *(const short8*)(Pin + (size_t)(g * 128 + 16 * w       + r) * 256 + kc + q * 8);
      short8 a1 = *(const short8*)(Pin + (size_t)(g * 128 + 16 * (w + 4) + r) * 256 + kc + q * 8);
      __syncthreads();
      #pragma unroll
      for (int nt = 0; nt < 4; ++nt){
        short8 bf = *(const short8*)&Bst[(16 * nt + r) * 40 + q * 8];
        acc0[nt] = __builtin_amdgcn_mfma_f32_16x16x32_bf16(a0, bf, acc0[nt], 0, 0, 0);
        acc1[nt] = __builtin_amdgcn_mfma_f32_16x16x32_bf16(a1, bf, acc1[nt], 0, 0, 0);
      }
    }
    __syncthreads();
    #pragma unroll
    for (int nt = 0; nt < 4; ++nt)
      #pragma unroll
      for (int i = 0; i < 4; ++i){
        HT_[(16 * nt + r) * 136 + 16 * w       + q * 4 + i] = f2b(acc0[nt][i]);
        HT_[(16 * nt + r) * 136 + 16 * (w + 4) + q * 4 + i] = f2b(acc1[nt][i]);
      }
    __syncthreads();
  }

  {
    float asv = Wbuf[WOFF_G2AS + lane];
    float adv = Wbuf[WOFF_G2AD + lane];
    for (int it = 0; it < 32; ++it){
      int n = it * 4 + w;
      float e0 = b2f(HT_[lane * 136 + n]);
      float vs = e0 * asv, vd = e0 * adv;
      #pragma unroll
      for (int m = 32; m >= 1; m >>= 1){ vs += __shfl_xor(vs, m); vd += __shfl_xor(vd, m); }
      if (lane == 0){ ALSf[n] = vs; ALDf[n] = vd; }
    }
  }
  __syncthreads();
  for (int i = tid; i < 8704; i += 256) ((unsigned int*)AD)[i] = 0;
  __syncthreads();
  if (tid < 128){
    int n = tid;
    float aldv = ALDf[n];
    int rs = rowL[n], re = rowL[n + 1];
    float mx = -3e38f, den = 0.f;
    for (int j = rs; j < re; ++j){
      float v = ALSf[srcL[j]] + aldv;
      v = v > 0.f ? v : 0.2f * v;
      if (v > mx){ den = den * __expf(mx - v) + 1.f; mx = v; }
      else den += __expf(v - mx);
    }
    float iden = 1.f / (den + 1e-16f);
    for (int j = rs; j < re; ++j){
      float v = ALSf[srcL[j]] + aldv;
      v = v > 0.f ? v : 0.2f * v;
      float al = __expf(v - mx) * iden;
      int s = srcL[j];
      AD[n * 136 + s] = f2b(b2f(AD[n * 136 + s]) + al);
    }
  }
  __syncthreads();
  float4v am[2][4];
  #pragma unroll
  for (int mt = 0; mt < 2; ++mt)
    #pragma unroll
    for (int nt = 0; nt < 4; ++nt) am[mt][nt] = (float4v){0,0,0,0};
  #pragma unroll
  for (int kc = 0; kc < 4; ++kc){
    short8 af0 = *(const short8*)&AD[(w * 32      + r) * 136 + kc * 32 + q * 8];
    short8 af1 = *(const short8*)&AD[(w * 32 + 16 + r) * 136 + kc * 32 + q * 8];
    #pragma unroll
    for (int nt = 0; nt < 4; ++nt){
      short8 bf = *(const short8*)&HT_[(nt * 16 + r) * 136 + kc * 32 + q * 8];
      am[0][nt] = __builtin_amdgcn_mfma_f32_16x16x32_bf16(af0, bf, am[0][nt], 0, 0, 0);
      am[1][nt] = __builtin_amdgcn_mfma_f32_16x16x32_bf16(af1, bf, am[1][nt], 0, 0, 0);
    }
  }
  float psum[4] = {0.f, 0.f, 0.f, 0.f};
  #pragma unroll
  for (int nt = 0; nt < 4; ++nt){
    int col = nt * 16 + r;
    float bz = Wbuf[WOFF_G2B + col];
    #pragma unroll
    for (int mt = 0; mt < 2; ++mt)
      #pragma unroll
      for (int i = 0; i < 4; ++i){
        float v = am[mt][nt][i] + bz;
        psum[nt] += (v > 0.f ? v : 0.f);
      }
    psum[nt] += __shfl_xor(psum[nt], 16);
    psum[nt] += __shfl_xor(psum[nt], 32);
  }
  if (q == 0){
    #pragma unroll
    for (int nt = 0; nt < 4; ++nt) pools[w][nt * 16 + r] = psum[nt];
  }
  __syncthreads();
  if (tid < 64 && (tid >> 5) == hb){
    float s = pools[0][tid] + pools[1][tid] + pools[2][tid] + pools[3][tid];
    int b = g >> 6, tq = g & 63;
    XSEQ[(size_t)(tq * BSZ + b) * HIDD + tid] = f2b(s);
  }
}

// ---------------- MFMA matmul for BOTH Wih GEMMs in one launch (z = dir) ----------------
__global__ __launch_bounds__(256)
void mmx2_kernel(const unsigned short* __restrict__ A,
                 const unsigned short* __restrict__ B0, const unsigned short* __restrict__ B1,
                 float* __restrict__ C0, float* __restrict__ C1, int M, int Nc, int K)
{
  __shared__ unsigned short As[64][40];
  __shared__ unsigned short Bs[64][40];
  const unsigned short* Bb = blockIdx.z ? B1 : B0;
  float* C = blockIdx.z ? C1 : C0;
  const int tid = threadIdx.x;
  const int w = tid >> 6, lane = tid & 63, q = lane >> 4, r = lane & 15;
  const int m0 = blockIdx.x * 64, n0 = blockIdx.y * 64;
  float4v acc0 = {0,0,0,0}, acc1 = {0,0,0,0}, acc2 = {0,0,0,0}, acc3 = {0,0,0,0};
  const int arow = tid >> 2, akb = (tid & 3) * 8;
  const int bk = tid >> 3, bnb = (tid & 7) * 8;
  for (int kc = 0; kc < K; kc += 32){
    int kw = K - kc; if (kw > 32) kw = 32;
    if (akb < kw){
      uint4 v = *(const uint4*)(A + (size_t)(m0 + arow) * K + kc + akb);
      *(uint4*)&As[arow][akb] = v;
    } else {
      uint4 z = {0,0,0,0}; *(uint4*)&As[arow][akb] = z;
    }
    if (bk < kw){
      uint4 v = *(const uint4*)(Bb + (size_t)(kc + bk) * Nc + n0 + bnb);
      const unsigned short* vs = (const unsigned short*)&v;
      #pragma unroll
      for (int e = 0; e < 8; ++e) Bs[bnb + e][bk] = vs[e];
    } else {
      #pragma unroll
      for (int e = 0; e < 8; ++e) Bs[bnb + e][bk] = 0;
    }
    __syncthreads();
    short8 af = *(const short8*)&As[16 * w + r][q * 8];
    short8 b0 = *(const short8*)&Bs[r][q * 8];
    short8 b1 = *(const short8*)&Bs[16 + r][q * 8];
    short8 b2 = *(const short8*)&Bs[32 + r][q * 8];
    short8 b3 = *(const short8*)&Bs[48 + r][q * 8];
    acc0 = __builtin_amdgcn_mfma_f32_16x16x32_bf16(af, b0, acc0, 0, 0, 0);
    acc1 = __builtin_amdgcn_mfma_f32_16x16x32_bf16(af, b1, acc1, 0, 0, 0);
    acc2 = __builtin_amdgcn_mfma_f32_16x16x32_bf16(af, b2, acc2, 0, 0, 0);
    acc3 = __builtin_amdgcn_mfma_f32_16x16x32_bf16(af, b3, acc3, 0, 0, 0);
    __syncthreads();
  }
  const int row = m0 + 16 * w + q * 4, col0 = n0 + r;
  #pragma unroll
  for (int i = 0; i < 4; ++i){
    size_t base = (size_t)(row + i) * Nc;
    C[base + col0]      = acc0[i];
    C[base + col0 + 16] = acc1[i];
    C[base + col0 + 32] = acc2[i];
    C[base + col0 + 48] = acc3[i];
  }
}

// ---------------- LSTM via MFMA + fused head: R21 step structure (Phase A first, 3 barriers) ----------------
__global__ __launch_bounds__(256)
void lstm14_kernel(const float* __restrict__ XF, const float* __restrict__ XB,
                   const unsigned int* __restrict__ WT,
                   const float* __restrict__ Wbuf,
                   unsigned int* __restrict__ HX,
                   float* __restrict__ HT,
                   float* __restrict__ out)
{
  __shared__ unsigned int WL[32768];
  __shared__ unsigned int H16[16 * 132];
  __shared__ float glds[4][256];
  __shared__ float muv[4][64];
  __shared__ float lvv[4][64];

  const int tid = threadIdx.x;
  const int m = blockIdx.x & 3, dir = blockIdx.x >> 2;
  const int w = tid >> 6, lane = tid & 63, quad = lane >> 4, r = lane & 15;
  const float* Xp = dir ? XB : XF;
  const int ub = tid >> 6, uj = tid & 63;
  unsigned int* HXd = HX + dir * 6144;
  int* DONE = (int*)(HX + 12288);

  const float* bi = Wbuf + (dir ? WOFF_BIHB : WOFF_BIHF);
  const float* bh = Wbuf + (dir ? WOFF_BHHB : WOFF_BHHF);
  float bias0 = bi[0 * 256 + 64 * m + uj] + bh[0 * 256 + 64 * m + uj];
  float bias1 = bi[1 * 256 + 64 * m + uj] + bh[1 * 256 + 64 * m + uj];
  float bias2 = bi[2 * 256 + 64 * m + uj] + bh[2 * 256 + 64 * m + uj];
  float bias3 = bi[3 * 256 + 64 * m + uj] + bh[3 * 256 + 64 * m + uj];

  {
    const uint4* WT4 = (const uint4*)(WT + dir * 131072 + m * 32768);
    uint4* WL4 = (uint4*)WL;
    #pragma unroll
    for (int s = 0; s < 32; ++s)
      WL4[s * 256 + tid] = WT4[s * 256 + tid];
  }
  for (int i = tid; i < 16 * 132; i += 256) H16[i] = 0;
  float c = 0.f;
  __syncthreads();

  const uint4* WL4 = (const uint4*)WL;
  const uint4* H16u4 = (const uint4*)H16;

  float4v acc[4];
  auto kchunk = [&](int kc){
    uint4 av = H16u4[(lane & 15) * 33 + kc * 4 + quad];
    short8 af = *(const short8*)&av;
    #pragma unroll
    for (int t = 0; t < 4; ++t){
      int nt = w * 4 + t;
      uint4 bv = WL4[(kc * 16 + nt) * 64 + lane];
      short8 bf = *(const short8*)&bv;
      acc[t] = __builtin_amdgcn_mfma_f32_16x16x32_bf16(af, bf, acc[t], 0, 0, 0);
    }
  };

  for (int t = 0; t < TT; ++t){
    const int tb = dir ? (TT - 1 - t) : t;
    const float* xr = Xp + (size_t)(tb * 4 + ub) * 1024 + 64 * m + uj;
    float x0 = xr[0], x1 = xr[256], x2 = xr[512], x3 = xr[768];

    #pragma unroll
    for (int i = 0; i < 4; ++i) acc[i] = (float4v){0,0,0,0};
    // Phase A: own k-range — peer-independent (overlaps peers' publish flight)
    kchunk(2 * m); kchunk(2 * m + 1);
    // Phase B: fetch peer slices of h(t-1), poll payload
    if (t > 0 && w > 0){
      int qp = (m + w) & 3;
      unsigned int* S = HXd + ((t - 1) % 3) * 2048 + m * 512;
      int b2 = lane >> 5, p2 = lane & 31;
      int i1G = b2 * 128 + 32 * qp + p2;
      int i2G = (b2 + 2) * 128 + 32 * qp + p2;
      int i1L = b2 * 132 + 32 * qp + p2;
      int i2L = (b2 + 2) * 132 + 32 * qp + p2;
      unsigned int v1, v2;
      int guard = 0;
      while ((v1 = __hip_atomic_load(&S[i1G], __ATOMIC_RELAXED, __HIP_MEMORY_SCOPE_AGENT)) == SENT
             && guard < 200000){ __builtin_amdgcn_s_sleep(1); ++guard; }
      guard = 0;
      while ((v2 = __hip_atomic_load(&S[i2G], __ATOMIC_RELAXED, __HIP_MEMORY_SCOPE_AGENT)) == SENT
             && guard < 200000){ __builtin_amdgcn_s_sleep(1); ++guard; }
      H16[i1L] = v1; H16[i2L] = v2;
      __hip_atomic_store(&S[i1G], SENT, __ATOMIC_RELAXED, __HIP_MEMORY_SCOPE_AGENT);
      __hip_atomic_store(&S[i2G], SENT, __ATOMIC_RELAXED, __HIP_MEMORY_SCOPE_AGENT);
    }
    __syncthreads();
    // Phase C: peer k-chunks
    #pragma unroll
    for (int i = 1; i < 4; ++i){
      int qp = (m + i) & 3;
      kchunk(2 * qp); kchunk(2 * qp + 1);
    }
    if (quad == 0){
      #pragma unroll
      for (int tt = 0; tt < 4; ++tt){
        int l = (w * 4 + tt) * 16 + r;
        glds[0][l] = acc[tt][0];
        glds[1][l] = acc[tt][1];
        glds[2][l] = acc[tt][2];
        glds[3][l] = acc[tt][3];
      }
    }
    __syncthreads();

    float gi = glds[ub][uj]        + bias0 + x0;
    float gf = glds[ub][64 + uj]   + bias1 + x1;
    float gg = glds[ub][128 + uj]  + bias2 + x2;
    float go = glds[ub][192 + uj]  + bias3 + x3;
    float si = 1.f / (1.f + __expf(-gi));
    float sf = 1.f / (1.f + __expf(-gf));
    float so = 1.f / (1.f + __expf(-go));
    float tg = 1.f - 2.f / (1.f + __expf(2.f * gg));
    c = sf * c + si * tg;
    float ch = 1.f - 2.f / (1.f + __expf(2.f * c));
    float hval = so * ch;
    if (t == TT - 1){
      HT[(size_t)(dir * 4 + ub) * RHID + (64 * m + uj)] = hval;
      break;
    }
    unsigned int own = f2b(hval);
    unsigned int partner = ((unsigned int)__shfl_xor((int)own, 1)) & 0xffffu;
    unsigned int* S = HXd + (t % 3) * 2048;
    if ((uj & 1) == 0){
      unsigned int v = own | (partner << 16);
      int p = uj >> 1;
      int idxG = ub * 128 + 32 * m + p;
      int idxL = ub * 132 + 32 * m + p;
      H16[idxL] = v;
      #pragma unroll
      for (int cns = 1; cns < 4; ++cns)
        __hip_atomic_store(&S[((m + cns) & 3) * 512 + idxG], v,
                           __ATOMIC_RELAXED, __HIP_MEMORY_SCOPE_AGENT);
    }
    __syncthreads();   // trailing barrier: own-slice H16 writes visible to next Phase A
  }

  // ---- fused head: all 8 WGs signal; block 0 computes mu/logvar + Poincare ----
  __syncthreads();                       // drains HT stores (vmcnt) before release
  if (tid == 0)
    __hip_atomic_fetch_add(DONE, 1, __ATOMIC_RELEASE, __HIP_MEMORY_SCOPE_AGENT);
  if (blockIdx.x != 0) return;
  if (tid == 0){
    int guard = 0;
    while (__hip_atomic_load(DONE, __ATOMIC_ACQUIRE, __HIP_MEMORY_SCOPE_AGENT) < 8
           && guard < 2000000){ __builtin_amdgcn_s_sleep(1); ++guard; }
  }
  __syncthreads();
  for (int job = w; job < 512; job += 4){
    int j = job & 63, b = (job >> 6) & 3, mat = job >> 8;
    const float* W = Wbuf + (mat ? WOFF_LVW : WOFF_MUW) + (size_t)j * 512;
    float s = 0.f;
    #pragma unroll
    for (int e = 0; e < 8; ++e){
      int dk = lane * 8 + e;
      float fv = HT[((dk >> 8) * 4 + b) * 256 + (dk & 255)];
      s += W[dk] * fv;
    }
    #pragma unroll
    for (int mm = 32; mm >= 1; mm >>= 1) s += __shfl_xor(s, mm);
    if (lane == 0){
      float v = s + Wbuf[(mat ? WOFF_LVB : WOFF_MUB) + j];
      if (mat) lvv[b][j] = v; else muv[b][j] = v;
    }
  }
  __syncthreads();
  {
    int b = tid >> 6, j = tid & 63;
    float mu = muv[b][j];
    float sq = mu * mu;
    #pragma unroll
    for (int mm = 32; mm >= 1; mm >>= 1) sq += __shfl_xor(sq, mm);
    float nrm = sqrtf(sq);
    const float mxn = 1.0f - 4e-3f;
    if (nrm > mxn) mu = mu / nrm * mxn;
    out[b * 64 + j] = mu;
    out[256 + b * 64 + j] = lvv[b][j];
  }
}

extern "C" void kernel_launch(void* const* d_in, const int* in_sizes, int n_in,
                              void* d_out, int out_size, void* d_ws, size_t ws_size,
                              hipStream_t stream)
{
  const int* ei = (const int*)d_in[1];

  float* FW   = (float*)d_ws;
  float* Wbuf = FW + FOFF_WBUF;
  int*   csr_row = (int*)(FW + FOFF_CSR);
  unsigned short* csr_src = (unsigned short*)(FW + FOFF_CSR + 132);
  float* XFp  = FW + FOFF_XFP;
  float* XBp  = FW + FOFF_XBP;
  float* HT   = FW + FOFF_HT;
  unsigned short* XSEQ = (unsigned short*)(FW + FOFF_XSEQ);
  unsigned short* PA   = (unsigned short*)(FW + FOFF_PA);
  unsigned short* PB   = (unsigned short*)(FW + FOFF_PB);
  unsigned short* Pb   = (unsigned short*)(FW + FOFF_P);
  unsigned int*   WT   = (unsigned int*)(FW + FOFF_WE);
  unsigned short* BBF  = (unsigned short*)(FW + FOFF_BBF);
  unsigned int*   HX   = (unsigned int*)(FW + FOFF_SYNC);

  CvtArgs ca;
  static const int wsz[24] = {4096,256,256,256, 65536,256,256,256, 16384,64,64,64,
                              65536,262144,1024,1024, 65536,262144,1024,1024,
                              32768,64,32768,64};
  {
    int acc = 0;
    for (int k = 0; k < 24; ++k){ ca.src[k] = d_in[2 + k]; ca.off[k] = acc; acc += wsz[k]; }
    ca.off[24] = acc;
  }
  int nblk = (SP_TOTAL + 255) / 256 + 1;
  setup_kernel<<<nblk, 256, 0, stream>>>(ca, Wbuf, BBF, Pb, WT, HX,
                                         d_in[0], ei, csr_row, csr_src);

  glayer_kernel<16><<<512, 256, 0, stream>>>(Pb, BBF + BOFF_G0, Wbuf,
                                             WOFF_G0AS, WOFF_G0AD, WOFF_G0B,
                                             csr_row, csr_src, PA);
  glayer_kernel<256><<<512, 256, 0, stream>>>(PA, BBF + BOFF_G1, Wbuf,
                                              WOFF_G1AS, WOFF_G1AD, WOFF_G1B,
                                              csr_row, csr_src, PB);
  glayer2_kernel<<<512, 256, 0, stream>>>(PB, BBF + BOFF_G2, Wbuf,
                                          csr_row, csr_src, XSEQ);

  mmx2_kernel<<<dim3(4, 16, 2), 256, 0, stream>>>(XSEQ, BBF + BOFF_WF, BBF + BOFF_WB,
                                                  XFp, XBp, 256, 1024, 64);

  // LSTM + fused head (writes d_out directly)
  lstm14_kernel<<<8, 256, 0, stream>>>(XFp, XBp, WT, Wbuf, HX, HT, (float*)d_out);
}

// Round 24
// 359.481 us; speedup vs baseline: 1.2750x; 1.2510x over previous
//
#include <hip/hip_runtime.h>
#include <hip/hip_bf16.h>

// ---- problem constants ----
#define BSZ 4
#define TT 64
#define NNODE 128
#define NFEAT 16
#define HIDD 64
#define NHEAD 4
#define RHID 256
#define LDIM 64
#define EPG 1024
#define NGRAPH (BSZ*TT)          // 256
#define NTOT (NGRAPH*NNODE)      // 32768
#define ESLOTS (EPG+NNODE)       // 1152

// ---- canonical fp32 weight buffer offsets (floats) ----
#define WOFF_G0W 0
#define WOFF_G0AS 4096
#define WOFF_G0AD 4352
#define WOFF_G0B 4608
#define WOFF_G1W 4864
#define WOFF_G1AS 70400
#define WOFF_G1AD 70656
#define WOFF_G1B 70912
#define WOFF_G2W 71168
#define WOFF_G2AS 87552
#define WOFF_G2AD 87616
#define WOFF_G2B 87680
#define WOFF_WIHF 87744
#define WOFF_WHHF 153280
#define WOFF_BIHF 415424
#define WOFF_BHHF 416448
#define WOFF_WIHB 417472
#define WOFF_WHHB 483008
#define WOFF_BIHB 745152
#define WOFF_BHHB 746176
#define WOFF_MUW 747200
#define WOFF_MUB 779968
#define WOFF_LVW 780032
#define WOFF_LVB 812800
#define WTOTAL   812864

// ---- workspace float offsets ----
#define FOFF_WBUF 4096
#define FOFF_CSR  1052672      // csr_row int[132], csr_src u16[1152]
#define FOFF_SYNC 1314816      // HX: 2*3*4*512 uints (sentinel protocol)
#define FOFF_WE   1576960      // WTB (bf16 B-frag Whh, 262144 uints)
#define FOFF_BBF  1900000      // bf16 B matrices (u16 view)
#define FOFF_XFP  2756608
#define FOFF_XBP  3018752
#define FOFF_HT   3280896
#define FOFF_XSEQ 3282944
#define FOFF_PA   3291136      // P0 [32768][256] bf16
#define FOFF_PB   5388288      // P1 [32768][256] bf16
#define FOFF_P    7485440      // X  [32768][16]  bf16

// bf16 B-matrix u16 offsets inside BBF (G0/G1/G2 stored TRANSPOSED [out][in])
#define BOFF_G0 0
#define BOFF_G1 4096
#define BOFF_G2 69632
#define BOFF_WF 86016
#define BOFF_WB 151552
#define BTOTAL  217088

// setup phases
#define SP_CVTX  (WTOTAL + BTOTAL)            // 1029952
#define SP_WHH   (SP_CVTX + NTOT*NFEAT)       // 1554240
#define SP_HX    (SP_WHH + 262144)            // 1816384
#define SP_TOTAL (SP_HX + 12288)              // 1828672

#define SENT 0xFFFFFFFFu

typedef __attribute__((ext_vector_type(8))) short short8;
typedef __attribute__((ext_vector_type(4))) float float4v;

__device__ __forceinline__ float b2f(unsigned short u){
  union { unsigned int i; float f; } v; v.i = ((unsigned int)u) << 16; return v.f;
}
__device__ __forceinline__ unsigned short f2b(float f){
  __hip_bfloat16 h = __float2bfloat16(f);
  union { __hip_bfloat16 h; unsigned short u; } v; v.h = h; return v.u;
}
__device__ __forceinline__ float ldf(const void* p, int i, int flag){
  return flag ? b2f(((const unsigned short*)p)[i]) : ((const float*)p)[i];
}
__device__ __forceinline__ float h2f(unsigned short s){
  union { _Float16 hh; unsigned short s; } u; u.s = s; return (float)u.hh;
}
__device__ __forceinline__ unsigned short f2h(float f){
  union { _Float16 hh; unsigned short s; } u; u.hh = (_Float16)f; return u.s;
}
__device__ __forceinline__ int sniff32(const unsigned short* w){
  int ok = 0;
  #pragma unroll
  for (int i = 0; i < 32; ++i){
    float a = fabsf(b2f(w[2 * i]));
    if (a > 1e-8f && a < 4.f) ok++;
  }
  return ok >= 16 ? 1 : 0;
}

// ---------------- fused setup: sniff + cvtw + packb(T) + cvtx + packwhh + HX + CSR ----------------
struct CvtArgs {
  const void* src[24];
  int off[25];
};
__global__ void setup_kernel(CvtArgs a,
                             float* __restrict__ W, unsigned short* __restrict__ BBF,
                             unsigned short* __restrict__ P, unsigned int* __restrict__ WT,
                             unsigned int* __restrict__ HX,
                             const void* __restrict__ x, const int* __restrict__ ei,
                             int* __restrict__ csr_row, unsigned short* __restrict__ csr_src)
{
  __shared__ int cnt[NNODE];
  __shared__ int off[NNODE];
  __shared__ int wo[NNODE];
  const int tid = threadIdx.x;

  if (blockIdx.x == gridDim.x - 1){
    if (tid < NNODE) cnt[tid] = 0;
    __syncthreads();
    for (int i = tid; i < ESLOTS; i += 256){
      int d = (i < EPG) ? ei[EPG + i] : (i - EPG);
      atomicAdd(&cnt[d], 1);
    }
    __syncthreads();
    if (tid < NNODE) off[tid] = cnt[tid];
    for (int o = 1; o < NNODE; o <<= 1){
      __syncthreads();
      int t = (tid < NNODE && tid >= o) ? off[tid - o] : 0;
      __syncthreads();
      if (tid < NNODE) off[tid] += t;
    }
    __syncthreads();
    if (tid < NNODE){
      wo[tid] = off[tid] - cnt[tid];
      csr_row[tid + 1] = off[tid];
    }
    if (tid == 0) csr_row[0] = 0;
    __syncthreads();
    for (int i = tid; i < ESLOTS; i += 256){
      int s, d;
      if (i < EPG){ s = ei[i]; d = ei[EPG + i]; } else { s = i - EPG; d = i - EPG; }
      int pos = atomicAdd(&wo[d], 1);
      csr_src[pos] = (unsigned short)s;
    }
    return;
  }

  int id = blockIdx.x * blockDim.x + tid;
  if (id >= SP_TOTAL) return;
  int fl = sniff32((const unsigned short*)a.src[0]);
  if (id < WTOTAL){
    int k = 0;
    while (id >= a.off[k + 1]) ++k;
    W[id] = ldf(a.src[k], id - a.off[k], fl);
  } else if (id < WTOTAL + BTOTAL){
    int r = id - WTOTAL;
    float v;
    if (r < BOFF_G1){
      int o = r >> 4, k = r & 15;
      v = ldf(a.src[0], k * 256 + o, fl);
    } else if (r < BOFF_G2){
      int rr = r - BOFF_G1; int o = rr >> 8, k = rr & 255;
      v = ldf(a.src[4], k * 256 + o, fl);
    } else if (r < BOFF_WF){
      int rr = r - BOFF_G2; int o = rr >> 8, k = rr & 255;
      v = ldf(a.src[8], k * 64 + o, fl);
    } else if (r < BOFF_WB){
      int q = r - BOFF_WF; int k = q >> 10, n = q & 1023;
      v = ldf(a.src[12], n * 64 + k, fl);
    } else {
      int q = r - BOFF_WB; int k = q >> 10, n = q & 1023;
      v = ldf(a.src[16], n * 64 + k, fl);
    }
    BBF[r] = f2b(v);
  } else if (id < SP_CVTX + NTOT * NFEAT){
    int r = id - SP_CVTX;
    P[r] = fl ? ((const unsigned short*)x)[r] : f2b(((const float*)x)[r]);
  } else if (id < SP_HX){
    int r0 = id - SP_WHH;
    int c = r0 & 3;
    int lane = (r0 >> 2) & 63;
    int nt = (r0 >> 8) & 15;
    int kc = (r0 >> 12) & 7;
    int m = (r0 >> 15) & 3;
    int dir = r0 >> 17;
    int l = nt * 16 + (lane & 15);
    int u = (l >> 6) * 256 + 64 * m + (l & 63);
    int k0 = kc * 32 + ((lane >> 4) << 3) + 2 * c;
    const void* Wsrc = dir ? a.src[17] : a.src[13];
    unsigned short va = f2b(ldf(Wsrc, u * RHID + k0, fl));
    unsigned short vb = f2b(ldf(Wsrc, u * RHID + k0 + 1, fl));
    WT[r0] = (unsigned int)va | ((unsigned int)vb << 16);
  } else {
    HX[id - SP_HX] = SENT;
  }
}

// ---------------- GAT 4-head half-layer kernel (L0/L1): 512 blocks, MFMA agg, plain stores ----------------
template<int KV>
__global__ __launch_bounds__(256)
void glayer_kernel(const unsigned short* __restrict__ Pin,
                   const unsigned short* __restrict__ BT,
                   const float* __restrict__ Wbuf,
                   int asoff, int adoff, int boff,
                   const int* __restrict__ csr_row, const unsigned short* __restrict__ csr_src,
                   unsigned short* __restrict__ Pout)
{
  __shared__ unsigned short HT_[128 * 136];   // h^T [col][node]
  __shared__ unsigned short AD[128 * 136];    // union: Bst / dense-alpha [dst][src]
  __shared__ unsigned short ALS16[256];
  __shared__ unsigned short ALD16[256];
  __shared__ int   rowL[132];
  __shared__ unsigned char srcL[1152];

  const int tid = threadIdx.x;
  const int g = blockIdx.x >> 1, hb = blockIdx.x & 1;
  const int c0 = hb * 128;
  const int w = tid >> 6, lane = tid & 63, q = lane >> 4, r = lane & 15;
  unsigned short* Bst = AD;

  for (int i = tid; i < 129; i += 256) rowL[i] = csr_row[i];
  for (int i = tid; i < 1152; i += 256) srcL[i] = (unsigned char)csr_src[i];
  __syncthreads();

  // ---- GEMM producing h^T ----
  {
    float4v acc0[8], acc1[8];
    #pragma unroll
    for (int i = 0; i < 8; ++i){ acc0[i] = (float4v){0,0,0,0}; acc1[i] = (float4v){0,0,0,0}; }
    const int KR = (KV + 31) / 32;
    for (int kr = 0; kr < KR; ++kr){
      const int kc = kr * 32;
      __syncthreads();
      {
        int n = tid >> 1, kb = (tid & 1) * 16;
        uint4 z = {0,0,0,0}; uint4 v0 = z, v1 = z;
        if (kb < KV)     v0 = *(const uint4*)(BT + (size_t)(c0 + n) * KV + kc + kb);
        if (kb + 8 < KV) v1 = *(const uint4*)(BT + (size_t)(c0 + n) * KV + kc + kb + 8);
        *(uint4*)&Bst[n * 40 + kb] = v0;
        *(uint4*)&Bst[n * 40 + kb + 8] = v1;
      }
      short8 a0 = {0,0,0,0,0,0,0,0}, a1 = {0,0,0,0,0,0,0,0};
      if (KV >= 32 || q < 2){
        a0 = *(const short8*)(Pin + (size_t)(g * 128 + 16 * w       + r) * KV + kc + q * 8);
        a1 = *(const short8*)(Pin + (size_t)(g * 128 + 16 * (w + 4) + r) * KV + kc + q * 8);
      }
      __syncthreads();
      #pragma unroll
      for (int nt = 0; nt < 8; ++nt){
        short8 bf = *(const short8*)&Bst[(16 * nt + r) * 40 + q * 8];
        acc0[nt] = __builtin_amdgcn_mfma_f32_16x16x32_bf16(a0, bf, acc0[nt], 0, 0, 0);
        acc1[nt] = __builtin_amdgcn_mfma_f32_16x16x32_bf16(a1, bf, acc1[nt], 0, 0, 0);
      }
    }
    __syncthreads();
    #pragma unroll
    for (int nt = 0; nt < 8; ++nt)
      #pragma unroll
      for (int i = 0; i < 4; ++i){
        HT_[(16 * nt + r) * 136 + 16 * w       + q * 4 + i] = f2b(acc0[nt][i]);
        HT_[(16 * nt + r) * 136 + 16 * (w + 4) + q * 4 + i] = f2b(acc1[nt][i]);
      }
    __syncthreads();
  }

  // ---- attention logits (2 local heads) ----
  {
    float as0 = Wbuf[asoff + c0 + 2 * lane], as1 = Wbuf[asoff + c0 + 2 * lane + 1];
    float ad0 = Wbuf[adoff + c0 + 2 * lane], ad1 = Wbuf[adoff + c0 + 2 * lane + 1];
    for (int it = 0; it < 32; ++it){
      int n = it * 4 + w;
      float e0 = b2f(HT_[(2 * lane) * 136 + n]);
      float e1 = b2f(HT_[(2 * lane + 1) * 136 + n]);
      float vs = e0 * as0 + e1 * as1;
      float vd = e0 * ad0 + e1 * ad1;
      #pragma unroll
      for (int m = 16; m >= 1; m >>= 1){ vs += __shfl_xor(vs, m); vd += __shfl_xor(vd, m); }
      if ((lane & 31) == 0){
        ALS16[n * 2 + (lane >> 5)] = f2h(vs);
        ALD16[n * 2 + (lane >> 5)] = f2h(vd);
      }
    }
  }
  __syncthreads();

  // ---- per-head: dense softmax scatter + MFMA agg + plain-store epilogue ----
  for (int hl = 0; hl < 2; ++hl){
    for (int i = tid; i < 8704; i += 256) ((unsigned int*)AD)[i] = 0;
    __syncthreads();
    if (tid < 128){
      int n = tid;
      float aldv = h2f(ALD16[n * 2 + hl]);
      int rs = rowL[n], re = rowL[n + 1];
      float mx = -3e38f, den = 0.f;
      for (int j = rs; j < re; ++j){
        float v = h2f(ALS16[srcL[j] * 2 + hl]) + aldv;
        v = v > 0.f ? v : 0.2f * v;
        if (v > mx){ den = den * __expf(mx - v) + 1.f; mx = v; }
        else den += __expf(v - mx);
      }
      float iden = 1.f / (den + 1e-16f);
      for (int j = rs; j < re; ++j){
        float v = h2f(ALS16[srcL[j] * 2 + hl]) + aldv;
        v = v > 0.f ? v : 0.2f * v;
        float al = __expf(v - mx) * iden;
        int s = srcL[j];
        AD[n * 136 + s] = f2b(b2f(AD[n * 136 + s]) + al);
      }
    }
    __syncthreads();
    float4v am[2][4];
    #pragma unroll
    for (int mt = 0; mt < 2; ++mt)
      #pragma unroll
      for (int nt = 0; nt < 4; ++nt) am[mt][nt] = (float4v){0,0,0,0};
    #pragma unroll
    for (int kc = 0; kc < 4; ++kc){
      short8 af0 = *(const short8*)&AD[(w * 32      + r) * 136 + kc * 32 + q * 8];
      short8 af1 = *(const short8*)&AD[(w * 32 + 16 + r) * 136 + kc * 32 + q * 8];
      #pragma unroll
      for (int nt = 0; nt < 4; ++nt){
        short8 bf = *(const short8*)&HT_[(hl * 64 + nt * 16 + r) * 136 + kc * 32 + q * 8];
        am[0][nt] = __builtin_amdgcn_mfma_f32_16x16x32_bf16(af0, bf, am[0][nt], 0, 0, 0);
        am[1][nt] = __builtin_amdgcn_mfma_f32_16x16x32_bf16(af1, bf, am[1][nt], 0, 0, 0);
      }
    }
    #pragma unroll
    for (int mt = 0; mt < 2; ++mt)
      #pragma unroll
      for (int nt = 0; nt < 4; ++nt){
        int col = hl * 64 + nt * 16 + r;
        float bz = Wbuf[boff + c0 + col];
        #pragma unroll
        for (int i = 0; i < 4; ++i){
          int dst = w * 32 + mt * 16 + q * 4 + i;
          float v = am[mt][nt][i] + bz;
          v = v > 0.f ? v : 0.f;
          Pout[(size_t)(g * 128 + dst) * 256 + c0 + col] = f2b(v);
        }
      }
    __syncthreads();
  }
}

// ---------------- GAT layer 2 (1 head) + pool: 512 blocks ----------------
__global__ __launch_bounds__(256)
void glayer2_kernel(const unsigned short* __restrict__ Pin,
                    const unsigned short* __restrict__ BT,
                    const float* __restrict__ Wbuf,
                    const int* __restrict__ csr_row, const unsigned short* __restrict__ csr_src,
                    unsigned short* __restrict__ XSEQ)
{
  __shared__ unsigned short HT_[64 * 136];
  __shared__ unsigned short AD[128 * 136];
  __shared__ float ALSf[128];
  __shared__ float ALDf[128];
  __shared__ int   rowL[132];
  __shared__ unsigned char srcL[1152];
  __shared__ float pools[4][64];

  const int tid = threadIdx.x;
  const int g = blockIdx.x >> 1, hb = blockIdx.x & 1;
  const int w = tid >> 6, lane = tid & 63, q = lane >> 4, r = lane & 15;
  unsigned short* Bst = AD;

  for (int i = tid; i < 129; i += 256) rowL[i] = csr_row[i];
  for (int i = tid; i < 1152; i += 256) srcL[i] = (unsigned char)csr_src[i];
  __syncthreads();

  // ---- GEMM h2^T [64 cols][128 nodes] ----
  {
    float4v acc0[4], acc1[4];
    #pragma unroll
    for (int i = 0; i < 4; ++i){ acc0[i] = (float4v){0,0,0,0}; acc1[i] = (float4v){0,0,0,0}; }
    for (int kr = 0; kr < 8; ++kr){
      const int kc = kr * 32;
      __syncthreads();
      {
        int n = tid >> 2, kb = (tid & 3) * 8;
        uint4 v = *(const uint4*)(BT + (size_t)n * 256 + kc + kb);
        *(uint4*)&Bst[n * 40 + kb] = v;
      }
      short8 a0 = *(const short8*)(Pin + (size_t)(g * 128 + 16 * w       + r) * 256 + kc + q * 8);
      short8 a1 = *(const short8*)(Pin + (size_t)(g * 128 + 16 * (w + 4) + r) * 256 + kc + q * 8);
      __syncthreads();
      #pragma unroll
      for (int nt = 0; nt < 4; ++nt){
        short8 bf = *(const short8*)&Bst[(16 * nt + r) * 40 + q * 8];
        acc0[nt] = __builtin_amdgcn_mfma_f32_16x16x32_bf16(a0, bf, acc0[nt], 0, 0, 0);
        acc1[nt] = __builtin_amdgcn_mfma_f32_16x16x32_bf16(a1, bf, acc1[nt], 0, 0, 0);
      }
    }
    __syncthreads();
    #pragma unroll
    for (int nt = 0; nt < 4; ++nt)
      #pragma unroll
      for (int i = 0; i < 4; ++i){
        HT_[(16 * nt + r) * 136 + 16 * w       + q * 4 + i] = f2b(acc0[nt][i]);
        HT_[(16 * nt + r) * 136 + 16 * (w + 4) + q * 4 + i] = f2b(acc1[nt][i]);
      }
    __syncthreads();
  }

  // ---- attention (64 cols) ----
  {
    float asv = Wbuf[WOFF_G2AS + lane];
    float adv = Wbuf[WOFF_G2AD + lane];
    for (int it = 0; it < 32; ++it){
      int n = it * 4 + w;
      float e0 = b2f(HT_[lane * 136 + n]);
      float vs = e0 * asv, vd = e0 * adv;
      #pragma unroll
      for (int m = 32; m >= 1; m >>= 1){ vs += __shfl_xor(vs, m); vd += __shfl_xor(vd, m); }
      if (lane == 0){ ALSf[n] = vs; ALDf[n] = vd; }
    }
  }
  __syncthreads();
  for (int i = tid; i < 8704; i += 256) ((unsigned int*)AD)[i] = 0;
  __syncthreads();
  if (tid < 128){
    int n = tid;
    float aldv = ALDf[n];
    int rs = rowL[n], re = rowL[n + 1];
    float mx = -3e38f, den = 0.f;
    for (int j = rs; j < re; ++j){
      float v = ALSf[srcL[j]] + aldv;
      v = v > 0.f ? v : 0.2f * v;
      if (v > mx){ den = den * __expf(mx - v) + 1.f; mx = v; }
      else den += __expf(v - mx);
    }
    float iden = 1.f / (den + 1e-16f);
    for (int j = rs; j < re; ++j){
      float v = ALSf[srcL[j]] + aldv;
      v = v > 0.f ? v : 0.2f * v;
      float al = __expf(v - mx) * iden;
      int s = srcL[j];
      AD[n * 136 + s] = f2b(b2f(AD[n * 136 + s]) + al);
    }
  }
  __syncthreads();
  float4v am[2][4];
  #pragma unroll
  for (int mt = 0; mt < 2; ++mt)
    #pragma unroll
    for (int nt = 0; nt < 4; ++nt) am[mt][nt] = (float4v){0,0,0,0};
  #pragma unroll
  for (int kc = 0; kc < 4; ++kc){
    short8 af0 = *(const short8*)&AD[(w * 32      + r) * 136 + kc * 32 + q * 8];
    short8 af1 = *(const short8*)&AD[(w * 32 + 16 + r) * 136 + kc * 32 + q * 8];
    #pragma unroll
    for (int nt = 0; nt < 4; ++nt){
      short8 bf = *(const short8*)&HT_[(nt * 16 + r) * 136 + kc * 32 + q * 8];
      am[0][nt] = __builtin_amdgcn_mfma_f32_16x16x32_bf16(af0, bf, am[0][nt], 0, 0, 0);
      am[1][nt] = __builtin_amdgcn_mfma_f32_16x16x32_bf16(af1, bf, am[1][nt], 0, 0, 0);
    }
  }
  float psum[4] = {0.f, 0.f, 0.f, 0.f};
  #pragma unroll
  for (int nt = 0; nt < 4; ++nt){
    int col = nt * 16 + r;
    float bz = Wbuf[WOFF_G2B + col];
    #pragma unroll
    for (int mt = 0; mt < 2; ++mt)
      #pragma unroll
      for (int i = 0; i < 4; ++i){
        float v = am[mt][nt][i] + bz;
        psum[nt] += (v > 0.f ? v : 0.f);
      }
    psum[nt] += __shfl_xor(psum[nt], 16);
    psum[nt] += __shfl_xor(psum[nt], 32);
  }
  if (q == 0){
    #pragma unroll
    for (int nt = 0; nt < 4; ++nt) pools[w][nt * 16 + r] = psum[nt];
  }
  __syncthreads();
  if (tid < 64 && (tid >> 5) == hb){
    float s = pools[0][tid] + pools[1][tid] + pools[2][tid] + pools[3][tid];
    int b = g >> 6, tq = g & 63;
    XSEQ[(size_t)(tq * BSZ + b) * HIDD + tid] = f2b(s);
  }
}

// ---------------- MFMA matmul for BOTH Wih GEMMs in one launch (z = dir) ----------------
__global__ __launch_bounds__(256)
void mmx2_kernel(const unsigned short* __restrict__ A,
                 const unsigned short* __restrict__ B0, const unsigned short* __restrict__ B1,
                 float* __restrict__ C0, float* __restrict__ C1, int M, int Nc, int K)
{
  __shared__ unsigned short As[64][40];
  __shared__ unsigned short Bs[64][40];
  const unsigned short* Bb = blockIdx.z ? B1 : B0;
  float* C = blockIdx.z ? C1 : C0;
  const int tid = threadIdx.x;
  const int w = tid >> 6, lane = tid & 63, q = lane >> 4, r = lane & 15;
  const int m0 = blockIdx.x * 64, n0 = blockIdx.y * 64;
  float4v acc0 = {0,0,0,0}, acc1 = {0,0,0,0}, acc2 = {0,0,0,0}, acc3 = {0,0,0,0};
  const int arow = tid >> 2, akb = (tid & 3) * 8;
  const int bk = tid >> 3, bnb = (tid & 7) * 8;
  for (int kc = 0; kc < K; kc += 32){
    int kw = K - kc; if (kw > 32) kw = 32;
    if (akb < kw){
      uint4 v = *(const uint4*)(A + (size_t)(m0 + arow) * K + kc + akb);
      *(uint4*)&As[arow][akb] = v;
    } else {
      uint4 z = {0,0,0,0}; *(uint4*)&As[arow][akb] = z;
    }
    if (bk < kw){
      uint4 v = *(const uint4*)(Bb + (size_t)(kc + bk) * Nc + n0 + bnb);
      const unsigned short* vs = (const unsigned short*)&v;
      #pragma unroll
      for (int e = 0; e < 8; ++e) Bs[bnb + e][bk] = vs[e];
    } else {
      #pragma unroll
      for (int e = 0; e < 8; ++e) Bs[bnb + e][bk] = 0;
    }
    __syncthreads();
    short8 af = *(const short8*)&As[16 * w + r][q * 8];
    short8 b0 = *(const short8*)&Bs[r][q * 8];
    short8 b1 = *(const short8*)&Bs[16 + r][q * 8];
    short8 b2 = *(const short8*)&Bs[32 + r][q * 8];
    short8 b3 = *(const short8*)&Bs[48 + r][q * 8];
    acc0 = __builtin_amdgcn_mfma_f32_16x16x32_bf16(af, b0, acc0, 0, 0, 0);
    acc1 = __builtin_amdgcn_mfma_f32_16x16x32_bf16(af, b1, acc1, 0, 0, 0);
    acc2 = __builtin_amdgcn_mfma_f32_16x16x32_bf16(af, b2, acc2, 0, 0, 0);
    acc3 = __builtin_amdgcn_mfma_f32_16x16x32_bf16(af, b3, acc3, 0, 0, 0);
    __syncthreads();
  }
  const int row = m0 + 16 * w + q * 4, col0 = n0 + r;
  #pragma unroll
  for (int i = 0; i < 4; ++i){
    size_t base = (size_t)(row + i) * Nc;
    C[base + col0]      = acc0[i];
    C[base + col0 + 16] = acc1[i];
    C[base + col0 + 32] = acc2[i];
    C[base + col0 + 48] = acc3[i];
  }
}

// ---------------- LSTM via MFMA: 8 WGs, sentinel sync; H16 rows padded (132 uints) ----------------
__global__ __launch_bounds__(256)
void lstm13_kernel(const float* __restrict__ XF, const float* __restrict__ XB,
                   const unsigned int* __restrict__ WT,
                   const float* __restrict__ bih_f, const float* __restrict__ bhh_f,
                   const float* __restrict__ bih_b, const float* __restrict__ bhh_b,
                   unsigned int* __restrict__ HX,
                   float* __restrict__ HT)
{
  __shared__ unsigned int WL[32768];
  __shared__ unsigned int H16[16 * 132];
  __shared__ float glds[4][256];

  const int tid = threadIdx.x;
  const int m = blockIdx.x & 3, dir = blockIdx.x >> 2;
  const int w = tid >> 6, lane = tid & 63, quad = lane >> 4, r = lane & 15;
  const float* Xp = dir ? XB : XF;
  const int ub = tid >> 6, uj = tid & 63;
  unsigned int* HXd = HX + dir * 6144;

  const float* bi = dir ? bih_b : bih_f;
  const float* bh = dir ? bhh_b : bhh_f;
  float bias0 = bi[0 * 256 + 64 * m + uj] + bh[0 * 256 + 64 * m + uj];
  float bias1 = bi[1 * 256 + 64 * m + uj] + bh[1 * 256 + 64 * m + uj];
  float bias2 = bi[2 * 256 + 64 * m + uj] + bh[2 * 256 + 64 * m + uj];
  float bias3 = bi[3 * 256 + 64 * m + uj] + bh[3 * 256 + 64 * m + uj];

  {
    const uint4* WT4 = (const uint4*)(WT + dir * 131072 + m * 32768);
    uint4* WL4 = (uint4*)WL;
    #pragma unroll
    for (int s = 0; s < 32; ++s)
      WL4[s * 256 + tid] = WT4[s * 256 + tid];
  }
  for (int i = tid; i < 16 * 132; i += 256) H16[i] = 0;
  float c = 0.f;
  __syncthreads();

  const uint4* WL4 = (const uint4*)WL;
  const uint4* H16u4 = (const uint4*)H16;

  float4v acc[4];
  auto kchunk = [&](int kc){
    uint4 av = H16u4[(lane & 15) * 33 + kc * 4 + quad];
    short8 af = *(const short8*)&av;
    #pragma unroll
    for (int t = 0; t < 4; ++t){
      int nt = w * 4 + t;
      uint4 bv = WL4[(kc * 16 + nt) * 64 + lane];
      short8 bf = *(const short8*)&bv;
      acc[t] = __builtin_amdgcn_mfma_f32_16x16x32_bf16(af, bf, acc[t], 0, 0, 0);
    }
  };

  for (int t = 0; t < TT; ++t){
    const int tb = dir ? (TT - 1 - t) : t;
    const float* xr = Xp + (size_t)(tb * 4 + ub) * 1024 + 64 * m + uj;
    float x0 = xr[0], x1 = xr[256], x2 = xr[512], x3 = xr[768];

    #pragma unroll
    for (int i = 0; i < 4; ++i) acc[i] = (float4v){0,0,0,0};
    kchunk(2 * m); kchunk(2 * m + 1);
    if (t > 0 && w > 0){
      int qp = (m + w) & 3;
      unsigned int* S = HXd + ((t - 1) % 3) * 2048 + m * 512;
      int b2 = lane >> 5, p2 = lane & 31;
      int i1G = b2 * 128 + 32 * qp + p2;
      int i2G = (b2 + 2) * 128 + 32 * qp + p2;
      int i1L = b2 * 132 + 32 * qp + p2;
      int i2L = (b2 + 2) * 132 + 32 * qp + p2;
      unsigned int v1, v2;
      int guard = 0;
      while ((v1 = __hip_atomic_load(&S[i1G], __ATOMIC_RELAXED, __HIP_MEMORY_SCOPE_AGENT)) == SENT
             && guard < 200000){ __builtin_amdgcn_s_sleep(1); ++guard; }
      guard = 0;
      while ((v2 = __hip_atomic_load(&S[i2G], __ATOMIC_RELAXED, __HIP_MEMORY_SCOPE_AGENT)) == SENT
             && guard < 200000){ __builtin_amdgcn_s_sleep(1); ++guard; }
      H16[i1L] = v1; H16[i2L] = v2;
      __hip_atomic_store(&S[i1G], SENT, __ATOMIC_RELAXED, __HIP_MEMORY_SCOPE_AGENT);
      __hip_atomic_store(&S[i2G], SENT, __ATOMIC_RELAXED, __HIP_MEMORY_SCOPE_AGENT);
    }
    __syncthreads();
    #pragma unroll
    for (int i = 1; i < 4; ++i){
      int qp = (m + i) & 3;
      kchunk(2 * qp); kchunk(2 * qp + 1);
    }
    if (quad == 0){
      #pragma unroll
      for (int tt = 0; tt < 4; ++tt){
        int l = (w * 4 + tt) * 16 + r;
        glds[0][l] = acc[tt][0];
        glds[1][l] = acc[tt][1];
        glds[2][l] = acc[tt][2];
        glds[3][l] = acc[tt][3];
      }
    }
    __syncthreads();

    float gi = glds[ub][uj]        + bias0 + x0;
    float gf = glds[ub][64 + uj]   + bias1 + x1;
    float gg = glds[ub][128 + uj]  + bias2 + x2;
    float go = glds[ub][192 + uj]  + bias3 + x3;
    float si = 1.f / (1.f + __expf(-gi));
    float sf = 1.f / (1.f + __expf(-gf));
    float so = 1.f / (1.f + __expf(-go));
    float tg = 1.f - 2.f / (1.f + __expf(2.f * gg));
    c = sf * c + si * tg;
    float ch = 1.f - 2.f / (1.f + __expf(2.f * c));
    float hval = so * ch;
    if (t == TT - 1){
      HT[(size_t)(dir * 4 + ub) * RHID + (64 * m + uj)] = hval;
      break;
    }
    unsigned int own = f2b(hval);
    unsigned int partner = ((unsigned int)__shfl_xor((int)own, 1)) & 0xffffu;
    unsigned int* S = HXd + (t % 3) * 2048;
    if ((uj & 1) == 0){
      unsigned int v = own | (partner << 16);
      int p = uj >> 1;
      int idxG = ub * 128 + 32 * m + p;
      int idxL = ub * 132 + 32 * m + p;
      H16[idxL] = v;
      #pragma unroll
      for (int cns = 1; cns < 4; ++cns)
        __hip_atomic_store(&S[((m + cns) & 3) * 512 + idxG], v,
                           __ATOMIC_RELAXED, __HIP_MEMORY_SCOPE_AGENT);
    }
    __syncthreads();
  }
}

// ---------------- heads + Poincare projection, fp32 out ----------------
__global__ __launch_bounds__(512)
void head2_kernel(const float* __restrict__ HT,
                  const float* __restrict__ muW, const float* __restrict__ mub,
                  const float* __restrict__ lvW, const float* __restrict__ lvb,
                  float* __restrict__ out)
{
  __shared__ float feat[4][512];
  __shared__ float muv[4][64];
  __shared__ float lvv[4][64];
  int tid = threadIdx.x;
  for (int i = tid; i < 2048; i += 512){
    int rr = i >> 8, k = i & 255;
    int b = rr & 3, d = rr >> 2;
    feat[b][d * 256 + k] = HT[i];
  }
  __syncthreads();
  int w = tid >> 6, lane = tid & 63;
  for (int job = w; job < 512; job += 8){
    int j = job & 63, b = (job >> 6) & 3, mat = job >> 8;
    const float* W = (mat ? lvW : muW) + (size_t)j * 512;
    float s = 0.f;
    #pragma unroll
    for (int e = 0; e < 8; ++e) s += W[lane * 8 + e] * feat[b][lane * 8 + e];
    #pragma unroll
    for (int mm = 32; mm >= 1; mm >>= 1) s += __shfl_xor(s, mm);
    if (lane == 0){
      float v = s + (mat ? lvb[j] : mub[j]);
      if (mat) lvv[b][j] = v; else muv[b][j] = v;
    }
  }
  __syncthreads();
  if (tid < 256){
    int b = tid >> 6, j = tid & 63;
    float mu = muv[b][j];
    float sq = mu * mu;
    #pragma unroll
    for (int mm = 32; mm >= 1; mm >>= 1) sq += __shfl_xor(sq, mm);
    float nrm = sqrtf(sq);
    const float mxn = 1.0f - 4e-3f;
    if (nrm > mxn) mu = mu / nrm * mxn;
    out[b * 64 + j] = mu;
    out[256 + b * 64 + j] = lvv[b][j];
  }
}

extern "C" void kernel_launch(void* const* d_in, const int* in_sizes, int n_in,
                              void* d_out, int out_size, void* d_ws, size_t ws_size,
                              hipStream_t stream)
{
  const int* ei = (const int*)d_in[1];

  float* FW   = (float*)d_ws;
  float* Wbuf = FW + FOFF_WBUF;
  int*   csr_row = (int*)(FW + FOFF_CSR);
  unsigned short* csr_src = (unsigned short*)(FW + FOFF_CSR + 132);
  float* XFp  = FW + FOFF_XFP;
  float* XBp  = FW + FOFF_XBP;
  float* HT   = FW + FOFF_HT;
  unsigned short* XSEQ = (unsigned short*)(FW + FOFF_XSEQ);
  unsigned short* PA   = (unsigned short*)(FW + FOFF_PA);
  unsigned short* PB   = (unsigned short*)(FW + FOFF_PB);
  unsigned short* Pb   = (unsigned short*)(FW + FOFF_P);
  unsigned int*   WT   = (unsigned int*)(FW + FOFF_WE);
  unsigned short* BBF  = (unsigned short*)(FW + FOFF_BBF);
  unsigned int*   HX   = (unsigned int*)(FW + FOFF_SYNC);

  CvtArgs ca;
  static const int wsz[24] = {4096,256,256,256, 65536,256,256,256, 16384,64,64,64,
                              65536,262144,1024,1024, 65536,262144,1024,1024,
                              32768,64,32768,64};
  {
    int acc = 0;
    for (int k = 0; k < 24; ++k){ ca.src[k] = d_in[2 + k]; ca.off[k] = acc; acc += wsz[k]; }
    ca.off[24] = acc;
  }
  int nblk = (SP_TOTAL + 255) / 256 + 1;
  setup_kernel<<<nblk, 256, 0, stream>>>(ca, Wbuf, BBF, Pb, WT, HX,
                                         d_in[0], ei, csr_row, csr_src);

  glayer_kernel<16><<<512, 256, 0, stream>>>(Pb, BBF + BOFF_G0, Wbuf,
                                             WOFF_G0AS, WOFF_G0AD, WOFF_G0B,
                                             csr_row, csr_src, PA);
  glayer_kernel<256><<<512, 256, 0, stream>>>(PA, BBF + BOFF_G1, Wbuf,
                                              WOFF_G1AS, WOFF_G1AD, WOFF_G1B,
                                              csr_row, csr_src, PB);
  glayer2_kernel<<<512, 256, 0, stream>>>(PB, BBF + BOFF_G2, Wbuf,
                                          csr_row, csr_src, XSEQ);

  mmx2_kernel<<<dim3(4, 16, 2), 256, 0, stream>>>(XSEQ, BBF + BOFF_WF, BBF + BOFF_WB,
                                                  XFp, XBp, 256, 1024, 64);

  lstm13_kernel<<<8, 256, 0, stream>>>(XFp, XBp, WT,
                                       Wbuf + WOFF_BIHF, Wbuf + WOFF_BHHF,
                                       Wbuf + WOFF_BIHB, Wbuf + WOFF_BHHB,
                                       HX, HT);

  head2_kernel<<<1, 512, 0, stream>>>(HT, Wbuf + WOFF_MUW, Wbuf + WOFF_MUB,
                                      Wbuf + WOFF_LVW, Wbuf + WOFF_LVB, (float*)d_out);
}